// Round 2
// baseline (926.385 us; speedup 1.0000x reference)
//
#include <hip/hip_runtime.h>
#include <hip/hip_bf16.h>
#include <cstdint>

// Problem constants
#define BB 8
#define CC 512
#define HH 96
#define NN 9216      // 96*96
#define HEADS 4
#define HD 128
#define KMAX 256     // c/2

typedef unsigned short ushort_t;
typedef __attribute__((ext_vector_type(8))) short bf16x8;
typedef __attribute__((ext_vector_type(4))) float f32x4;

__device__ __forceinline__ unsigned short f2bf(float f) {
  unsigned int u = __float_as_uint(f);
  u += 0x7fffu + ((u >> 16) & 1u);   // RNE; values are finite here
  return (unsigned short)(u >> 16);
}
__device__ __forceinline__ float bf2f(unsigned short s) {
  return __uint_as_float(((unsigned int)s) << 16);
}
__device__ __forceinline__ unsigned int pk2(float lo, float hi) {
  return (unsigned int)f2bf(lo) | ((unsigned int)f2bf(hi) << 16);
}

// async global->LDS 16B: lds dest must be wave-uniform base; HW scatters lane i at +16*i
__device__ __forceinline__ void gld16(const void* g, void* l) {
  __builtin_amdgcn_global_load_lds(
      (const __attribute__((address_space(1))) unsigned int*)(uintptr_t)g,
      (__attribute__((address_space(3))) unsigned int*)(unsigned int)(uintptr_t)l,
      16, 0, 0);
}

// ---------------- rope table: cos/sin[col][kk], col = pos % 96 ----------------
__global__ void rope_table_k(float* __restrict__ rope) {
  int t = blockIdx.x * 256 + threadIdx.x;
  if (t >= HH * KMAX) return;
  int col = t >> 8;
  int kk = t & (KMAX - 1);
  float theta = powf(10000.0f, -((float)kk) / (float)KMAX);
  float ang = (float)col * theta;
  float s, c;
  sincosf(ang, &s, &c);
  rope[2 * t] = c;
  rope[2 * t + 1] = s;
}

// ---------------- W fp32 -> bf16 ----------------------------------------------
__global__ void conv_w_k(const float* __restrict__ W, unsigned short* __restrict__ Wbf) {
  int t = blockIdx.x * 256 + threadIdx.x;  // 131072 float4s
  float4 v = *(const float4*)(W + (size_t)t * 4);
  unsigned int lo = (unsigned int)f2bf(v.x) | ((unsigned int)f2bf(v.y) << 16);
  unsigned int hi = (unsigned int)f2bf(v.z) | ((unsigned int)f2bf(v.w) << 16);
  *(uint2*)(Wbf + (size_t)t * 4) = make_uint2(lo, hi);
}

// ---------------- per-batch transpose: x[b][ch][pos] fp32 -> xt[pos][ch] bf16 --
__global__ void transpose_xb_k(const float* __restrict__ x, unsigned short* __restrict__ xt,
                               int b) {
  __shared__ unsigned short T[64 * 72];  // [pos][ch], pad 8 (row 144B, 16B-aligned)
  const int pos0 = blockIdx.x * 64;
  const int ch0 = blockIdx.y * 64;
  const int tid = threadIdx.x;
#pragma unroll
  for (int i = 0; i < 4; ++i) {
    int fi = i * 256 + tid;          // 0..1023
    int ch = fi >> 4, p4 = fi & 15;  // 64 ch x 16 float4
    float4 v = *(const float4*)(x + ((size_t)b * CC + ch0 + ch) * NN + pos0 + p4 * 4);
    T[(p4 * 4 + 0) * 72 + ch] = f2bf(v.x);
    T[(p4 * 4 + 1) * 72 + ch] = f2bf(v.y);
    T[(p4 * 4 + 2) * 72 + ch] = f2bf(v.z);
    T[(p4 * 4 + 3) * 72 + ch] = f2bf(v.w);
  }
  __syncthreads();
#pragma unroll
  for (int i = 0; i < 2; ++i) {
    int s = i * 256 + tid;          // 0..511
    int p = s >> 3, cc = s & 7;     // 64 rows x 8 chunks of 16B
    uint4 u = *(const uint4*)&T[p * 72 + cc * 8];
    *(uint4*)(xt + (size_t)(pos0 + p) * CC + ch0 + cc * 8) = u;
  }
}

// ---------------- qk GEMM (MFMA bf16): C[m,j] = sum_ch xt[m,ch]*Wbf[j,ch] ------
__launch_bounds__(256)
__global__ void gemm_qk_mfma(const unsigned short* __restrict__ xt,
                             const unsigned short* __restrict__ Wbf,
                             const float* __restrict__ bqk,
                             unsigned short* __restrict__ qout,
                             unsigned short* __restrict__ kout, int b) {
  __shared__ __align__(16) unsigned short sA[128 * 64];
  __shared__ __align__(16) unsigned short sB[128 * 64];
  const int tid = threadIdx.x;
  const int wv = tid >> 6, lane = tid & 63;
  const int bn = blockIdx.x;        // 0..7 (j blocks)
  const int m0 = blockIdx.y * 128;  // pos within batch
  const int j0 = bn * 128;
  const int row = lane & 15, quad = lane >> 4;
  const int mt0 = (wv & 1) * 64, nt0 = (wv >> 1) * 64;
  f32x4 acc[4][4];
#pragma unroll
  for (int mi = 0; mi < 4; ++mi)
#pragma unroll
    for (int ni = 0; ni < 4; ++ni) acc[mi][ni] = (f32x4){0.f, 0.f, 0.f, 0.f};

  for (int kt = 0; kt < CC; kt += 64) {
#pragma unroll
    for (int it = 0; it < 4; ++it) {
      int s = it * 256 + tid;                 // LDS slot (16B units)
      int srow = s >> 3;                      // tile row 0..127
      int sc = (s & 7) ^ (srow & 7);          // swizzled chunk -> global chunk
      int ldsoff = (it * 256 + wv * 64) * 8;  // wave-uniform base (ushort units)
      gld16(xt + (size_t)(m0 + srow) * CC + kt + sc * 8, &sA[ldsoff]);
      gld16(Wbf + (size_t)(j0 + srow) * CC + kt + sc * 8, &sB[ldsoff]);
    }
    __syncthreads();
#pragma unroll
    for (int ks = 0; ks < 2; ++ks) {
      bf16x8 af[4], bf[4];
      const int chunk = (ks * 4 + quad) ^ (row & 7);
#pragma unroll
      for (int mi = 0; mi < 4; ++mi)
        af[mi] = *(const bf16x8*)&sA[((mt0 + mi * 16 + row) * 8 + chunk) * 8];
#pragma unroll
      for (int ni = 0; ni < 4; ++ni)
        bf[ni] = *(const bf16x8*)&sB[((nt0 + ni * 16 + row) * 8 + chunk) * 8];
#pragma unroll
      for (int mi = 0; mi < 4; ++mi)
#pragma unroll
        for (int ni = 0; ni < 4; ++ni)
          acc[mi][ni] = __builtin_amdgcn_mfma_f32_16x16x32_bf16(af[mi], bf[ni], acc[mi][ni], 0, 0, 0);
    }
    __syncthreads();
  }
  // epilogue: bias + elu+1, bf16 store. C/D layout: col=lane&15, row=quad*4+reg.
  unsigned short* dst = (j0 < CC) ? qout : kout;
  const int jl = (j0 & (CC - 1)) + nt0;
  float bj[4];
#pragma unroll
  for (int ni = 0; ni < 4; ++ni) bj[ni] = bqk[j0 + nt0 + ni * 16 + row];
#pragma unroll
  for (int mi = 0; mi < 4; ++mi) {
#pragma unroll
    for (int ni = 0; ni < 4; ++ni) {
#pragma unroll
      for (int r = 0; r < 4; ++r) {
        float v = acc[mi][ni][r] + bj[ni];
        v = v > 0.f ? v + 1.f : expm1f(v) + 1.f;
        int mrow = m0 + mt0 + mi * 16 + quad * 4 + r;
        dst[((size_t)b * NN + mrow) * CC + jl + ni * 16 + row] = f2bf(v);
      }
    }
  }
}

// ---------------- k_mean 2-stage over weird flat reshape ----------------------
__global__ void kmean_p1_k(const unsigned short* __restrict__ kbf, float* __restrict__ part) {
  __shared__ float red[256];
  const int seg = blockIdx.x;  // 0..17
  const int bh = blockIdx.y;   // 0..31
  const int b = bh >> 2, head = bh & 3;
  const int tid = threadIdx.x;
  const int d = tid & 127, half = tid >> 7;
  const unsigned short* base =
      kbf + ((size_t)b * NN + head * 2304 + seg * 128 + half * 64) * CC + d;
  float sum = 0.f;
  for (int pp = 0; pp < 64; ++pp) {
    const unsigned short* rp = base + (size_t)pp * CC;
    sum += bf2f(rp[0]) + bf2f(rp[128]) + bf2f(rp[256]) + bf2f(rp[384]);
  }
  red[tid] = sum;
  __syncthreads();
  if (half == 0) part[((size_t)bh * 18 + seg) * 128 + d] = red[d] + red[d + 128];
}

__global__ void kmean_p2_k(const float* __restrict__ part, float* __restrict__ kmean) {
  int idx = blockIdx.x * 256 + threadIdx.x;  // 4096
  int bh = idx >> 7, d = idx & 127;
  float s = 0.f;
#pragma unroll
  for (int i = 0; i < 18; ++i) s += part[((size_t)bh * 18 + i) * 128 + d];
  kmean[idx] = s * (1.0f / 9216.0f);
}

// ---------------- z[bh,p] = 1/(q2[bh,p,:].kmean[bh,:] + 1e-6) -----------------
__global__ void z_k(const unsigned short* __restrict__ qbf, const float* __restrict__ kmean,
                    float* __restrict__ z) {
  const int wv = threadIdx.x >> 6, lane = threadIdx.x & 63;
  const int zbase = (blockIdx.x * 4 + wv) * 8;
  const int bh = zbase / NN;
  const int p0 = zbase % NN;
  const int b = bh >> 2, head = bh & 3;
  const float km0 = kmean[bh * 128 + lane * 2];
  const float km1 = kmean[bh * 128 + lane * 2 + 1];
#pragma unroll
  for (int it = 0; it < 8; ++it) {
    const int p = p0 + it;
    const int pos = head * 2304 + (p >> 2);
    const int chb = (p & 3) * 128;
    const unsigned short* qp = qbf + ((size_t)b * NN + pos) * CC + chb + lane * 2;
    float dot = bf2f(qp[0]) * km0 + bf2f(qp[1]) * km1;
#pragma unroll
    for (int off = 1; off < 64; off <<= 1) dot += __shfl_xor(dot, off, 64);
    if (lane == 0) z[zbase + it] = 1.0f / (dot + 1e-6f);
  }
}

// ---------------- kv partials via MFMA ----------------------------------------
// kvp[s][bh][e][d] = sum_{q in seg} V[q][e] * Krope[q][d]
// q-order: q = r*2304 + t with p = 4t + r, so V[q][e] = x[b, r*128+e, head*2304+t]
// is k-contiguous (global-direct A frags, cvt fp32->bf16). Krope is built in
// registers from kbf rows (each thread owns 4 output d-rows x 8 q: the rope
// pair (re,im) IS two d-rows, so the transpose is free), then ds_write_b128
// into octet-swizzled sK[d][q] for conflict-free b128 B-frag reads.
__launch_bounds__(256, 2)
__global__ void kv_mfma_k(const unsigned short* __restrict__ kbf, const float* __restrict__ x,
                          const float* __restrict__ rope, float* __restrict__ kvp) {
  __shared__ __align__(16) unsigned short sK[128 * 64];  // [d 128][q 64], swizzled octets
  const int s = blockIdx.x;   // 0..15 (q segment)
  const int bh = blockIdx.y;  // 0..31
  const int b = bh >> 2, head = bh & 3;
  const int tid = threadIdx.x;
  const int wv = tid >> 6, lane = tid & 63;
  const int row = lane & 15, quad = lane >> 4;
  const int e0 = (wv & 1) * 64, d0 = (wv >> 1) * 64;
  const int r = s >> 2;           // p = 4t + r
  const int t0 = (s & 3) * 576;   // t range [t0, t0+576), 9 chunks of 64

  // staging role: this thread owns q-octet qg (8 q) x 4 d-rows (2 rope pairs)
  const int qg = tid & 7;
  const int dg = (tid >> 3) * 4;  // first d row (0,4,..,124)
  const unsigned short* kbase = kbf + (size_t)b * NN * CC + head * HD + dg;
  const int pairb = head * 64 + (dg >> 1);

  f32x4 acc[4][4];
#pragma unroll
  for (int mi = 0; mi < 4; ++mi)
#pragma unroll
    for (int ni = 0; ni < 4; ++ni) acc[mi][ni] = (f32x4){0.f, 0.f, 0.f, 0.f};

  for (int ck = 0; ck < 9; ++ck) {
    const int tc = t0 + ck * 64;
    // ---- issue V (A-operand) global loads early: 8 frags x 32B fp32 ----
    float4 a0[8], a1[8];
#pragma unroll
    for (int mi = 0; mi < 4; ++mi)
#pragma unroll
      for (int ks = 0; ks < 2; ++ks) {
        const float* xp = x + (size_t)(b * CC + r * 128 + e0 + mi * 16 + row) * NN +
                          head * 2304 + tc + ks * 32 + quad * 8;
        a0[mi * 2 + ks] = *(const float4*)xp;
        a1[mi * 2 + ks] = *(const float4*)(xp + 4);
      }
    // ---- K staging: rope in fp32, transpose-by-ownership, 4 b128 writes ----
    {
      int p = 4 * (tc + qg * 8) + r;
      int col = p % 96;
      float rw0[8], rw1[8], rw2[8], rw3[8];
#pragma unroll
      for (int j = 0; j < 8; ++j) {
        uint2 kv2 = *(const uint2*)(kbase + (size_t)p * CC);
        const float* rp = rope + ((size_t)col * KMAX + pairb) * 2;
        float4 cs = *(const float4*)rp;  // c0 s0 c1 s1
        float re0 = bf2f((unsigned short)(kv2.x & 0xffffu));
        float im0 = bf2f((unsigned short)(kv2.x >> 16));
        float re1 = bf2f((unsigned short)(kv2.y & 0xffffu));
        float im1 = bf2f((unsigned short)(kv2.y >> 16));
        rw0[j] = cs.x * re0 - cs.y * im0;
        rw1[j] = cs.y * re0 + cs.x * im0;
        rw2[j] = cs.z * re1 - cs.w * im1;
        rw3[j] = cs.w * re1 + cs.z * im1;
        p += 4;
        col += 4;
        col = (col >= 96) ? col - 96 : col;
      }
#pragma unroll
      for (int rr = 0; rr < 4; ++rr) {
        const float* rw = (rr == 0) ? rw0 : (rr == 1) ? rw1 : (rr == 2) ? rw2 : rw3;
        const int d = dg + rr;
        uint4 pk;
        pk.x = pk2(rw[0], rw[1]);
        pk.y = pk2(rw[2], rw[3]);
        pk.z = pk2(rw[4], rw[5]);
        pk.w = pk2(rw[6], rw[7]);
        *(uint4*)&sK[(d * 8 + (qg ^ (d & 7))) * 8] = pk;
      }
    }
    __syncthreads();
    // ---- MFMA phase ----
#pragma unroll
    for (int ks = 0; ks < 2; ++ks) {
      bf16x8 bfr[4];
#pragma unroll
      for (int ni = 0; ni < 4; ++ni) {
        const int d = d0 + ni * 16 + row;
        const int o = (ks * 4 + quad) ^ (d & 7);
        bfr[ni] = *(const bf16x8*)&sK[(d * 8 + o) * 8];
      }
#pragma unroll
      for (int mi = 0; mi < 4; ++mi) {
        const int f = mi * 2 + ks;
        union { bf16x8 v; unsigned int u[4]; } af;
        af.u[0] = pk2(a0[f].x, a0[f].y);
        af.u[1] = pk2(a0[f].z, a0[f].w);
        af.u[2] = pk2(a1[f].x, a1[f].y);
        af.u[3] = pk2(a1[f].z, a1[f].w);
#pragma unroll
        for (int ni = 0; ni < 4; ++ni)
          acc[mi][ni] = __builtin_amdgcn_mfma_f32_16x16x32_bf16(af.v, bfr[ni], acc[mi][ni], 0, 0, 0);
      }
    }
    __syncthreads();  // protect sK before next chunk's writes
  }
  // epilogue: D layout col(n=d)=lane&15, row(m=e)=quad*4+reg -> kvp[e][d]
  float* dst = kvp + (size_t)(s * 32 + bh) * (HD * HD);
#pragma unroll
  for (int mi = 0; mi < 4; ++mi) {
#pragma unroll
    for (int ni = 0; ni < 4; ++ni) {
#pragma unroll
      for (int rr = 0; rr < 4; ++rr) {
        const int e = e0 + mi * 16 + quad * 4 + rr;
        const int d = d0 + ni * 16 + row;
        dst[e * HD + d] = acc[mi][ni][rr];
      }
    }
  }
}

// ---------------- kv reduce: sum partials (already [e][d]), emit bf16 ---------
__global__ void kv_reduce_k(const float* __restrict__ kvp, unsigned short* __restrict__ kvtb) {
  int idx = blockIdx.x * 256 + threadIdx.x;  // 524288 = 32*128*128
  float ssum = 0.f;
#pragma unroll
  for (int i = 0; i < 16; ++i) ssum += kvp[(size_t)i * (32 * HD * HD) + idx];
  kvtb[idx] = f2bf(ssum * (1.0f / 9216.0f));
}

// ---------------- out+lepe fused ----------------------------------------------
// MFMA: out_attn[e,pos] = z[pos] * sum_d qrope[pos,d] * kvt[e,d]  (as before).
// Then z-scaled acc is staged through a 64x132 fp32 LDS tile (two e-half passes)
// to remap from MFMA fragment layout -> (ch, 4 consecutive pos) per thread, the
// 3x3 depthwise conv of x is computed in fp32 (identical math to old lepe_k),
// and out is written ONCE as coalesced float4. Saves the 302 MB out RMW pass.
__launch_bounds__(256)
__global__ void out_lepe_k(const unsigned short* __restrict__ qbf,
                           const unsigned short* __restrict__ kvtb,
                           const float* __restrict__ z, const float* __restrict__ rope,
                           const float* __restrict__ x, const float* __restrict__ lw,
                           const float* __restrict__ lb, float* __restrict__ out) {
  __shared__ __align__(16) float Ts[64 * 132];  // [eL][p], pad 4 (row 528B)
  const int bh = blockIdx.y, b = bh >> 2, head = bh & 3;
  const int pos0 = blockIdx.x * 128;
  const int tid = threadIdx.x, wv = tid >> 6, lane = tid & 63;
  const int row = lane & 15, quad = lane >> 4;
  const int e0 = (wv & 1) * 64;
  const int p0 = (wv >> 1) * 64;
  f32x4 acc[4][4];
#pragma unroll
  for (int mi = 0; mi < 4; ++mi)
#pragma unroll
    for (int ni = 0; ni < 4; ++ni) acc[mi][ni] = (f32x4){0.f, 0.f, 0.f, 0.f};

  int posn[4], coln[4];
#pragma unroll
  for (int ni = 0; ni < 4; ++ni) {
    posn[ni] = pos0 + p0 + ni * 16 + row;
    coln[ni] = posn[ni] % 96;
  }

#pragma unroll
  for (int kt = 0; kt < HD; kt += 32) {
    bf16x8 af[4], bfr[4];
#pragma unroll
    for (int mi = 0; mi < 4; ++mi)
      af[mi] = *(const bf16x8*)&kvtb[((size_t)bh * HD + e0 + mi * 16 + row) * HD + kt + quad * 8];
#pragma unroll
    for (int ni = 0; ni < 4; ++ni) {
      const uint4 u = *(const uint4*)(qbf + ((size_t)b * NN + posn[ni]) * CC +
                                      head * HD + kt + quad * 8);
      const int pairb = head * 64 + (kt >> 1) + quad * 4;
      const float* rp = rope + ((size_t)coln[ni] * KMAX + pairb) * 2;
      float4 r0 = *(const float4*)rp;        // c0 s0 c1 s1
      float4 r1 = *(const float4*)(rp + 4);  // c2 s2 c3 s3
      unsigned int uu[4] = {u.x, u.y, u.z, u.w};
      float cs[8] = {r0.x, r0.y, r0.z, r0.w, r1.x, r1.y, r1.z, r1.w};
      bf16x8 bb;
#pragma unroll
      for (int pr = 0; pr < 4; ++pr) {
        float re = bf2f((unsigned short)(uu[pr] & 0xffffu));
        float im = bf2f((unsigned short)(uu[pr] >> 16));
        float c = cs[2 * pr], s = cs[2 * pr + 1];
        bb[2 * pr] = (short)f2bf(c * re - s * im);
        bb[2 * pr + 1] = (short)f2bf(s * re + c * im);
      }
      bfr[ni] = bb;
    }
#pragma unroll
    for (int mi = 0; mi < 4; ++mi)
#pragma unroll
      for (int ni = 0; ni < 4; ++ni)
        acc[mi][ni] = __builtin_amdgcn_mfma_f32_16x16x32_bf16(af[mi], bfr[ni], acc[mi][ni], 0, 0, 0);
  }
  // z-scale in registers
#pragma unroll
  for (int ni = 0; ni < 4; ++ni) {
    const float zn = z[(size_t)bh * NN + posn[ni]];
#pragma unroll
    for (int mi = 0; mi < 4; ++mi)
#pragma unroll
      for (int r = 0; r < 4; ++r) acc[mi][ni][r] *= zn;
  }

  // two e-half passes through LDS; lepe conv + single coalesced out write
  const int t5 = tid >> 5, tl = tid & 31;
#pragma unroll
  for (int h = 0; h < 2; ++h) {
    if ((wv & 1) == h) {
#pragma unroll
      for (int mi = 0; mi < 4; ++mi)
#pragma unroll
        for (int ni = 0; ni < 4; ++ni)
#pragma unroll
          for (int r = 0; r < 4; ++r) {
            const int eL = mi * 16 + quad * 4 + r;
            const int p = p0 + ni * 16 + row;
            Ts[eL * 132 + p] = acc[mi][ni][r];
          }
    }
    __syncthreads();
#pragma unroll 2
    for (int i = 0; i < 8; ++i) {
      const int eL = i * 8 + t5;
      const int ch = head * HD + h * 64 + eL;
      const int pos = pos0 + tl * 4;
      const int pi = pos / 96;
      const int pj = pos - pi * 96;  // multiple of 4
      const float* wp = lw + ch * 9;
      float w[9];
#pragma unroll
      for (int t = 0; t < 9; ++t) w[t] = wp[t];
      const float* xp = x + ((size_t)b * CC + ch) * NN;
      const float bias = lb[ch];
      float a0 = bias, a1 = bias, a2 = bias, a3 = bias;
#pragma unroll
      for (int rr = 0; rr < 3; ++rr) {
        const int y = pi + rr - 1;
        if ((unsigned)y >= 96u) continue;
        const float* rowp = xp + y * 96 + pj;
        float4 M = *(const float4*)rowp;
        float Lv = (pj > 0) ? rowp[-1] : 0.f;
        float Rv = (pj < 92) ? rowp[4] : 0.f;
        const float w0 = w[rr * 3 + 0], w1 = w[rr * 3 + 1], w2 = w[rr * 3 + 2];
        a0 += w0 * Lv + w1 * M.x + w2 * M.y;
        a1 += w0 * M.x + w1 * M.y + w2 * M.z;
        a2 += w0 * M.y + w1 * M.z + w2 * M.w;
        a3 += w0 * M.z + w1 * M.w + w2 * Rv;
      }
      const float4 attn = *(const float4*)&Ts[eL * 132 + tl * 4];
      float4 o;
      o.x = attn.x + a0;
      o.y = attn.y + a1;
      o.z = attn.z + a2;
      o.w = attn.w + a3;
      *(float4*)(out + ((size_t)b * CC + ch) * NN + pos) = o;
    }
    __syncthreads();
  }
}

extern "C" void kernel_launch(void* const* d_in, const int* in_sizes, int n_in,
                              void* d_out, int out_size, void* d_ws, size_t ws_size,
                              hipStream_t stream) {
  const float* x = (const float*)d_in[0];
  const float* Wqk = (const float*)d_in[1];
  const float* bqk = (const float*)d_in[2];
  const float* lw = (const float*)d_in[3];
  const float* lb = (const float*)d_in[4];
  float* out = (float*)d_out;
  char* ws = (char*)d_ws;
  // ws layout (≈189 MB peak; xtb + kmean partials overlay the kvp region,
  // which is only live from kv_mfma_k onward; kvtb overlays old kv slot):
  unsigned short* qbf = (unsigned short*)(ws);                 // 75,497,472 B
  unsigned short* kbf = (unsigned short*)(ws + 75497472);      // 75,497,472 B
  float* rope = (float*)(ws + 150994944);                      //    196,608 B
  float* kmean = (float*)(ws + 151191552);                     //     16,384 B
  float* z = (float*)(ws + 151207936);                         //  1,179,648 B
  float* kvp = (float*)(ws + 152387584);                       // 33,554,432 B
  unsigned short* xtb = (unsigned short*)(ws + 152387584);     //  9,437,184 B (overlay)
  float* kmean_part = (float*)(ws + 152387584 + 16777216);     //    294,912 B (overlay)
  unsigned short* kvtb = (unsigned short*)(ws + 185942016);    //  1,048,576 B
  unsigned short* Wbf = (unsigned short*)(ws + 188039168);     //  1,048,576 B

  conv_w_k<<<dim3(512), dim3(256), 0, stream>>>(Wqk, Wbf);
  rope_table_k<<<dim3(96), dim3(256), 0, stream>>>(rope);
  for (int b = 0; b < BB; ++b) {
    transpose_xb_k<<<dim3(144, 8), dim3(256), 0, stream>>>(x, xtb, b);
    gemm_qk_mfma<<<dim3(8, 72), dim3(256), 0, stream>>>(xtb, Wbf, bqk, qbf, kbf, b);
  }
  kmean_p1_k<<<dim3(18, 32), dim3(256), 0, stream>>>(kbf, kmean_part);
  kmean_p2_k<<<dim3(16), dim3(256), 0, stream>>>(kmean_part, kmean);
  z_k<<<dim3(9216), dim3(256), 0, stream>>>(qbf, kmean, z);
  kv_mfma_k<<<dim3(16, 32), dim3(256), 0, stream>>>(kbf, x, rope, kvp);
  kv_reduce_k<<<dim3(2048), dim3(256), 0, stream>>>(kvp, kvtb);
  out_lepe_k<<<dim3(72, 32), dim3(256), 0, stream>>>(qbf, kvtb, z, rope, x, lw, lb, out);
}

// Round 3
// 736.234 us; speedup vs baseline: 1.2583x; 1.2583x over previous
//
#include <hip/hip_runtime.h>
#include <hip/hip_bf16.h>
#include <cstdint>

// Problem constants
#define BB 8
#define CC 512
#define HH 96
#define NN 9216      // 96*96
#define HEADS 4
#define HD 128
#define KMAX 256     // c/2

typedef unsigned short ushort_t;
typedef __attribute__((ext_vector_type(8))) short bf16x8;
typedef __attribute__((ext_vector_type(4))) float f32x4;

__device__ __forceinline__ unsigned short f2bf(float f) {
  unsigned int u = __float_as_uint(f);
  u += 0x7fffu + ((u >> 16) & 1u);   // RNE; values are finite here
  return (unsigned short)(u >> 16);
}
__device__ __forceinline__ float bf2f(unsigned short s) {
  return __uint_as_float(((unsigned int)s) << 16);
}
__device__ __forceinline__ unsigned int pk2(float lo, float hi) {
  return (unsigned int)f2bf(lo) | ((unsigned int)f2bf(hi) << 16);
}

// async global->LDS 16B: lds dest must be wave-uniform base; HW scatters lane i at +16*i
__device__ __forceinline__ void gld16(const void* g, void* l) {
  __builtin_amdgcn_global_load_lds(
      (const __attribute__((address_space(1))) unsigned int*)(uintptr_t)g,
      (__attribute__((address_space(3))) unsigned int*)(unsigned int)(uintptr_t)l,
      16, 0, 0);
}

// ---------------- rope table: cos/sin[col][kk], col = pos % 96 ----------------
__global__ void rope_table_k(float* __restrict__ rope) {
  int t = blockIdx.x * 256 + threadIdx.x;
  if (t >= HH * KMAX) return;
  int col = t >> 8;
  int kk = t & (KMAX - 1);
  float theta = powf(10000.0f, -((float)kk) / (float)KMAX);
  float ang = (float)col * theta;
  float s, c;
  sincosf(ang, &s, &c);
  rope[2 * t] = c;
  rope[2 * t + 1] = s;
}

// ---------------- W fp32 -> bf16 ----------------------------------------------
__global__ void conv_w_k(const float* __restrict__ W, unsigned short* __restrict__ Wbf) {
  int t = blockIdx.x * 256 + threadIdx.x;  // 131072 float4s
  float4 v = *(const float4*)(W + (size_t)t * 4);
  unsigned int lo = (unsigned int)f2bf(v.x) | ((unsigned int)f2bf(v.y) << 16);
  unsigned int hi = (unsigned int)f2bf(v.z) | ((unsigned int)f2bf(v.w) << 16);
  *(uint2*)(Wbf + (size_t)t * 4) = make_uint2(lo, hi);
}

// ------- all-batch transpose: x[b][ch][pos] fp32 -> xt[b][pos][ch] bf16 -------
__global__ void transpose_all_k(const float* __restrict__ x, unsigned short* __restrict__ xt) {
  __shared__ unsigned short T[64 * 72];  // [pos][ch], pad 8 (row 144B, 16B-aligned)
  const int pos0 = blockIdx.x * 64;
  const int ch0 = blockIdx.y * 64;
  const int b = blockIdx.z;
  const int tid = threadIdx.x;
#pragma unroll
  for (int i = 0; i < 4; ++i) {
    int fi = i * 256 + tid;          // 0..1023
    int ch = fi >> 4, p4 = fi & 15;  // 64 ch x 16 float4
    float4 v = *(const float4*)(x + ((size_t)b * CC + ch0 + ch) * NN + pos0 + p4 * 4);
    T[(p4 * 4 + 0) * 72 + ch] = f2bf(v.x);
    T[(p4 * 4 + 1) * 72 + ch] = f2bf(v.y);
    T[(p4 * 4 + 2) * 72 + ch] = f2bf(v.z);
    T[(p4 * 4 + 3) * 72 + ch] = f2bf(v.w);
  }
  __syncthreads();
#pragma unroll
  for (int i = 0; i < 2; ++i) {
    int s = i * 256 + tid;          // 0..511
    int p = s >> 3, cc = s & 7;     // 64 rows x 8 chunks of 16B
    uint4 u = *(const uint4*)&T[p * 72 + cc * 8];
    *(uint4*)(xt + ((size_t)b * NN + pos0 + p) * CC + ch0 + cc * 8) = u;
  }
}

// ---------------- qk GEMM (MFMA bf16): C[m,j] = sum_ch xt[m,ch]*Wbf[j,ch] ------
// one dispatch for all batches: blockIdx.z = b (4608 blocks, ~18/CU)
__launch_bounds__(256)
__global__ void gemm_qk_mfma(const unsigned short* __restrict__ xtall,
                             const unsigned short* __restrict__ Wbf,
                             const float* __restrict__ bqk,
                             unsigned short* __restrict__ qout,
                             unsigned short* __restrict__ kout) {
  __shared__ __align__(16) unsigned short sA[128 * 64];
  __shared__ __align__(16) unsigned short sB[128 * 64];
  const int tid = threadIdx.x;
  const int wv = tid >> 6, lane = tid & 63;
  const int bn = blockIdx.x;        // 0..7 (j blocks)
  const int m0 = blockIdx.y * 128;  // pos within batch
  const int b = blockIdx.z;
  const int j0 = bn * 128;
  const unsigned short* xt = xtall + (size_t)b * NN * CC;
  const int row = lane & 15, quad = lane >> 4;
  const int mt0 = (wv & 1) * 64, nt0 = (wv >> 1) * 64;
  f32x4 acc[4][4];
#pragma unroll
  for (int mi = 0; mi < 4; ++mi)
#pragma unroll
    for (int ni = 0; ni < 4; ++ni) acc[mi][ni] = (f32x4){0.f, 0.f, 0.f, 0.f};

  for (int kt = 0; kt < CC; kt += 64) {
#pragma unroll
    for (int it = 0; it < 4; ++it) {
      int s = it * 256 + tid;                 // LDS slot (16B units)
      int srow = s >> 3;                      // tile row 0..127
      int sc = (s & 7) ^ (srow & 7);          // swizzled chunk -> global chunk
      int ldsoff = (it * 256 + wv * 64) * 8;  // wave-uniform base (ushort units)
      gld16(xt + (size_t)(m0 + srow) * CC + kt + sc * 8, &sA[ldsoff]);
      gld16(Wbf + (size_t)(j0 + srow) * CC + kt + sc * 8, &sB[ldsoff]);
    }
    __syncthreads();
#pragma unroll
    for (int ks = 0; ks < 2; ++ks) {
      bf16x8 af[4], bf[4];
      const int chunk = (ks * 4 + quad) ^ (row & 7);
#pragma unroll
      for (int mi = 0; mi < 4; ++mi)
        af[mi] = *(const bf16x8*)&sA[((mt0 + mi * 16 + row) * 8 + chunk) * 8];
#pragma unroll
      for (int ni = 0; ni < 4; ++ni)
        bf[ni] = *(const bf16x8*)&sB[((nt0 + ni * 16 + row) * 8 + chunk) * 8];
#pragma unroll
      for (int mi = 0; mi < 4; ++mi)
#pragma unroll
        for (int ni = 0; ni < 4; ++ni)
          acc[mi][ni] = __builtin_amdgcn_mfma_f32_16x16x32_bf16(af[mi], bf[ni], acc[mi][ni], 0, 0, 0);
    }
    __syncthreads();
  }
  // epilogue: bias + elu+1, bf16 store. C/D layout: col=lane&15, row=quad*4+reg.
  unsigned short* dst = (j0 < CC) ? qout : kout;
  const int jl = (j0 & (CC - 1)) + nt0;
  float bj[4];
#pragma unroll
  for (int ni = 0; ni < 4; ++ni) bj[ni] = bqk[j0 + nt0 + ni * 16 + row];
#pragma unroll
  for (int mi = 0; mi < 4; ++mi) {
#pragma unroll
    for (int ni = 0; ni < 4; ++ni) {
#pragma unroll
      for (int r = 0; r < 4; ++r) {
        float v = acc[mi][ni][r] + bj[ni];
        v = v > 0.f ? v + 1.f : expm1f(v) + 1.f;
        int mrow = m0 + mt0 + mi * 16 + quad * 4 + r;
        dst[((size_t)b * NN + mrow) * CC + jl + ni * 16 + row] = f2bf(v);
      }
    }
  }
}

// ---------------- k_mean 2-stage over weird flat reshape ----------------------
__global__ void kmean_p1_k(const unsigned short* __restrict__ kbf, float* __restrict__ part) {
  __shared__ float red[256];
  const int seg = blockIdx.x;  // 0..17
  const int bh = blockIdx.y;   // 0..31
  const int b = bh >> 2, head = bh & 3;
  const int tid = threadIdx.x;
  const int d = tid & 127, half = tid >> 7;
  const unsigned short* base =
      kbf + ((size_t)b * NN + head * 2304 + seg * 128 + half * 64) * CC + d;
  float sum = 0.f;
  for (int pp = 0; pp < 64; ++pp) {
    const unsigned short* rp = base + (size_t)pp * CC;
    sum += bf2f(rp[0]) + bf2f(rp[128]) + bf2f(rp[256]) + bf2f(rp[384]);
  }
  red[tid] = sum;
  __syncthreads();
  if (half == 0) part[((size_t)bh * 18 + seg) * 128 + d] = red[d] + red[d + 128];
}

__global__ void kmean_p2_k(const float* __restrict__ part, float* __restrict__ kmean) {
  int idx = blockIdx.x * 256 + threadIdx.x;  // 4096
  int bh = idx >> 7, d = idx & 127;
  float s = 0.f;
#pragma unroll
  for (int i = 0; i < 18; ++i) s += part[((size_t)bh * 18 + i) * 128 + d];
  kmean[idx] = s * (1.0f / 9216.0f);
}

// ---------------- z[bh,p] = 1/(q2[bh,p,:].kmean[bh,:] + 1e-6) -----------------
__global__ void z_k(const unsigned short* __restrict__ qbf, const float* __restrict__ kmean,
                    float* __restrict__ z) {
  const int wv = threadIdx.x >> 6, lane = threadIdx.x & 63;
  const int zbase = (blockIdx.x * 4 + wv) * 8;
  const int bh = zbase / NN;
  const int p0 = zbase % NN;
  const int b = bh >> 2, head = bh & 3;
  const float km0 = kmean[bh * 128 + lane * 2];
  const float km1 = kmean[bh * 128 + lane * 2 + 1];
#pragma unroll
  for (int it = 0; it < 8; ++it) {
    const int p = p0 + it;
    const int pos = head * 2304 + (p >> 2);
    const int chb = (p & 3) * 128;
    const unsigned short* qp = qbf + ((size_t)b * NN + pos) * CC + chb + lane * 2;
    float dot = bf2f(qp[0]) * km0 + bf2f(qp[1]) * km1;
#pragma unroll
    for (int off = 1; off < 64; off <<= 1) dot += __shfl_xor(dot, off, 64);
    if (lane == 0) z[zbase + it] = 1.0f / (dot + 1e-6f);
  }
}

// ---------------- kv partials via MFMA ----------------------------------------
// kvp[s][bh][e][d] = sum_{q in seg} V[q][e] * Krope[q][d]
// q-order: q = r*2304 + t with p = 4t + r, so V[q][e] = x[b, r*128+e, head*2304+t]
// is k-contiguous (global-direct A frags, cvt fp32->bf16). Krope is built in
// registers from kbf rows (each thread owns 4 output d-rows x 8 q: the rope
// pair (re,im) IS two d-rows, so the transpose is free), then ds_write_b128
// into octet-swizzled sK[d][q] for conflict-free b128 B-frag reads.
__launch_bounds__(256, 2)
__global__ void kv_mfma_k(const unsigned short* __restrict__ kbf, const float* __restrict__ x,
                          const float* __restrict__ rope, float* __restrict__ kvp) {
  __shared__ __align__(16) unsigned short sK[128 * 64];  // [d 128][q 64], swizzled octets
  const int s = blockIdx.x;   // 0..15 (q segment)
  const int bh = blockIdx.y;  // 0..31
  const int b = bh >> 2, head = bh & 3;
  const int tid = threadIdx.x;
  const int wv = tid >> 6, lane = tid & 63;
  const int row = lane & 15, quad = lane >> 4;
  const int e0 = (wv & 1) * 64, d0 = (wv >> 1) * 64;
  const int r = s >> 2;           // p = 4t + r
  const int t0 = (s & 3) * 576;   // t range [t0, t0+576), 9 chunks of 64

  // staging role: this thread owns q-octet qg (8 q) x 4 d-rows (2 rope pairs)
  const int qg = tid & 7;
  const int dg = (tid >> 3) * 4;  // first d row (0,4,..,124)
  const unsigned short* kbase = kbf + (size_t)b * NN * CC + head * HD + dg;
  const int pairb = head * 64 + (dg >> 1);

  f32x4 acc[4][4];
#pragma unroll
  for (int mi = 0; mi < 4; ++mi)
#pragma unroll
    for (int ni = 0; ni < 4; ++ni) acc[mi][ni] = (f32x4){0.f, 0.f, 0.f, 0.f};

  for (int ck = 0; ck < 9; ++ck) {
    const int tc = t0 + ck * 64;
    // ---- issue V (A-operand) global loads early: 8 frags x 32B fp32 ----
    float4 a0[8], a1[8];
#pragma unroll
    for (int mi = 0; mi < 4; ++mi)
#pragma unroll
      for (int ks = 0; ks < 2; ++ks) {
        const float* xp = x + (size_t)(b * CC + r * 128 + e0 + mi * 16 + row) * NN +
                          head * 2304 + tc + ks * 32 + quad * 8;
        a0[mi * 2 + ks] = *(const float4*)xp;
        a1[mi * 2 + ks] = *(const float4*)(xp + 4);
      }
    // ---- K staging: rope in fp32, transpose-by-ownership, 4 b128 writes ----
    {
      int p = 4 * (tc + qg * 8) + r;
      int col = p % 96;
      float rw0[8], rw1[8], rw2[8], rw3[8];
#pragma unroll
      for (int j = 0; j < 8; ++j) {
        uint2 kv2 = *(const uint2*)(kbase + (size_t)p * CC);
        const float* rp = rope + ((size_t)col * KMAX + pairb) * 2;
        float4 cs = *(const float4*)rp;  // c0 s0 c1 s1
        float re0 = bf2f((unsigned short)(kv2.x & 0xffffu));
        float im0 = bf2f((unsigned short)(kv2.x >> 16));
        float re1 = bf2f((unsigned short)(kv2.y & 0xffffu));
        float im1 = bf2f((unsigned short)(kv2.y >> 16));
        rw0[j] = cs.x * re0 - cs.y * im0;
        rw1[j] = cs.y * re0 + cs.x * im0;
        rw2[j] = cs.z * re1 - cs.w * im1;
        rw3[j] = cs.w * re1 + cs.z * im1;
        p += 4;
        col += 4;
        col = (col >= 96) ? col - 96 : col;
      }
#pragma unroll
      for (int rr = 0; rr < 4; ++rr) {
        const float* rw = (rr == 0) ? rw0 : (rr == 1) ? rw1 : (rr == 2) ? rw2 : rw3;
        const int d = dg + rr;
        uint4 pk;
        pk.x = pk2(rw[0], rw[1]);
        pk.y = pk2(rw[2], rw[3]);
        pk.z = pk2(rw[4], rw[5]);
        pk.w = pk2(rw[6], rw[7]);
        *(uint4*)&sK[(d * 8 + (qg ^ (d & 7))) * 8] = pk;
      }
    }
    __syncthreads();
    // ---- MFMA phase ----
#pragma unroll
    for (int ks = 0; ks < 2; ++ks) {
      bf16x8 bfr[4];
#pragma unroll
      for (int ni = 0; ni < 4; ++ni) {
        const int d = d0 + ni * 16 + row;
        const int o = (ks * 4 + quad) ^ (d & 7);
        bfr[ni] = *(const bf16x8*)&sK[(d * 8 + o) * 8];
      }
#pragma unroll
      for (int mi = 0; mi < 4; ++mi) {
        const int f = mi * 2 + ks;
        union { bf16x8 v; unsigned int u[4]; } af;
        af.u[0] = pk2(a0[f].x, a0[f].y);
        af.u[1] = pk2(a0[f].z, a0[f].w);
        af.u[2] = pk2(a1[f].x, a1[f].y);
        af.u[3] = pk2(a1[f].z, a1[f].w);
#pragma unroll
        for (int ni = 0; ni < 4; ++ni)
          acc[mi][ni] = __builtin_amdgcn_mfma_f32_16x16x32_bf16(af.v, bfr[ni], acc[mi][ni], 0, 0, 0);
      }
    }
    __syncthreads();  // protect sK before next chunk's writes
  }
  // epilogue: D layout col(n=d)=lane&15, row(m=e)=quad*4+reg -> kvp[e][d]
  float* dst = kvp + (size_t)(s * 32 + bh) * (HD * HD);
#pragma unroll
  for (int mi = 0; mi < 4; ++mi) {
#pragma unroll
    for (int ni = 0; ni < 4; ++ni) {
#pragma unroll
      for (int rr = 0; rr < 4; ++rr) {
        const int e = e0 + mi * 16 + quad * 4 + rr;
        const int d = d0 + ni * 16 + row;
        dst[e * HD + d] = acc[mi][ni][rr];
      }
    }
  }
}

// ---------------- kv reduce: sum partials (already [e][d]), emit bf16 ---------
__global__ void kv_reduce_k(const float* __restrict__ kvp, unsigned short* __restrict__ kvtb) {
  int idx = blockIdx.x * 256 + threadIdx.x;  // 524288 = 32*128*128
  float ssum = 0.f;
#pragma unroll
  for (int i = 0; i < 16; ++i) ssum += kvp[(size_t)i * (32 * HD * HD) + idx];
  kvtb[idx] = f2bf(ssum * (1.0f / 9216.0f));
}

// ---------------- out (MFMA): out[b, head*128+e, pos] = z * sum_d qrope*kv ----
// m = e (A from kvtb[bh][e][d], k-contig), n = pos (B from rope(q), k-contig).
// No LDS; A/B frags read straight from global (kvtb is 1 MB, L2/L3-hot).
__launch_bounds__(256)
__global__ void out_mfma_k(const unsigned short* __restrict__ qbf,
                           const unsigned short* __restrict__ kvtb,
                           const float* __restrict__ z, const float* __restrict__ rope,
                           float* __restrict__ out) {
  const int bh = blockIdx.y, b = bh >> 2, head = bh & 3;
  const int pos0 = blockIdx.x * 128;
  const int tid = threadIdx.x, wv = tid >> 6, lane = tid & 63;
  const int row = lane & 15, quad = lane >> 4;
  const int e0 = (wv & 1) * 64;
  const int p0 = (wv >> 1) * 64;
  f32x4 acc[4][4];
#pragma unroll
  for (int mi = 0; mi < 4; ++mi)
#pragma unroll
    for (int ni = 0; ni < 4; ++ni) acc[mi][ni] = (f32x4){0.f, 0.f, 0.f, 0.f};

  int posn[4], coln[4];
#pragma unroll
  for (int ni = 0; ni < 4; ++ni) {
    posn[ni] = pos0 + p0 + ni * 16 + row;
    coln[ni] = posn[ni] % 96;
  }

#pragma unroll
  for (int kt = 0; kt < HD; kt += 32) {
    bf16x8 af[4], bfr[4];
#pragma unroll
    for (int mi = 0; mi < 4; ++mi)
      af[mi] = *(const bf16x8*)&kvtb[((size_t)bh * HD + e0 + mi * 16 + row) * HD + kt + quad * 8];
#pragma unroll
    for (int ni = 0; ni < 4; ++ni) {
      const uint4 u = *(const uint4*)(qbf + ((size_t)b * NN + posn[ni]) * CC +
                                      head * HD + kt + quad * 8);
      const int pairb = head * 64 + (kt >> 1) + quad * 4;
      const float* rp = rope + ((size_t)coln[ni] * KMAX + pairb) * 2;
      float4 r0 = *(const float4*)rp;        // c0 s0 c1 s1
      float4 r1 = *(const float4*)(rp + 4);  // c2 s2 c3 s3
      unsigned int uu[4] = {u.x, u.y, u.z, u.w};
      float cs[8] = {r0.x, r0.y, r0.z, r0.w, r1.x, r1.y, r1.z, r1.w};
      bf16x8 bb;
#pragma unroll
      for (int pr = 0; pr < 4; ++pr) {
        float re = bf2f((unsigned short)(uu[pr] & 0xffffu));
        float im = bf2f((unsigned short)(uu[pr] >> 16));
        float c = cs[2 * pr], s = cs[2 * pr + 1];
        bb[2 * pr] = (short)f2bf(c * re - s * im);
        bb[2 * pr + 1] = (short)f2bf(s * re + c * im);
      }
      bfr[ni] = bb;
    }
#pragma unroll
    for (int mi = 0; mi < 4; ++mi)
#pragma unroll
      for (int ni = 0; ni < 4; ++ni)
        acc[mi][ni] = __builtin_amdgcn_mfma_f32_16x16x32_bf16(af[mi], bfr[ni], acc[mi][ni], 0, 0, 0);
  }
  float zv[4];
#pragma unroll
  for (int ni = 0; ni < 4; ++ni) zv[ni] = z[(size_t)bh * NN + posn[ni]];
#pragma unroll
  for (int mi = 0; mi < 4; ++mi) {
#pragma unroll
    for (int ni = 0; ni < 4; ++ni) {
#pragma unroll
      for (int r = 0; r < 4; ++r) {
        int e = e0 + mi * 16 + quad * 4 + r;
        out[((size_t)b * CC + head * HD + e) * NN + posn[ni]] = acc[mi][ni][r] * zv[ni];
      }
    }
  }
}

// ---------------- lepe: depthwise 3x3 conv of x, ADDS into d_out --------------
// ILP-oriented: per thread 4 outputs from 3 rows x (float4 + 2 edge scalars);
// round-2 version was latency-bound at VGPR=8 (36 dependent scalar loads).
__global__ void lepe_k(const float* __restrict__ x, const float* __restrict__ lw,
                       const float* __restrict__ lb, float* __restrict__ out) {
  const int blk = blockIdx.x;  // B*C*9
  const int bc = blk / 9;
  const int tile = blk - bc * 9;
  const int ch = bc & (CC - 1);
  const float* wp = lw + ch * 9;
  float w[9];
#pragma unroll
  for (int t = 0; t < 9; ++t) w[t] = wp[t];
  const float bias = lb[ch];
  const float* xp = x + (size_t)bc * NN;
  const int pos = tile * 1024 + threadIdx.x * 4;
  const int pi = pos / 96;
  const int pj = pos - pi * 96;  // multiple of 4

  float4 o = *(const float4*)(out + (size_t)bc * NN + pos);  // RMW read early

  float a0 = bias, a1 = bias, a2 = bias, a3 = bias;
#pragma unroll
  for (int r = 0; r < 3; ++r) {
    const int y = pi + r - 1;
    if ((unsigned)y >= 96u) continue;
    const float* rowp = xp + y * 96 + pj;
    float4 M = *(const float4*)rowp;
    float Lv = (pj > 0) ? rowp[-1] : 0.f;
    float Rv = (pj < 92) ? rowp[4] : 0.f;
    const float w0 = w[r * 3 + 0], w1 = w[r * 3 + 1], w2 = w[r * 3 + 2];
    a0 += w0 * Lv + w1 * M.x + w2 * M.y;
    a1 += w0 * M.x + w1 * M.y + w2 * M.z;
    a2 += w0 * M.y + w1 * M.z + w2 * M.w;
    a3 += w0 * M.z + w1 * M.w + w2 * Rv;
  }
  o.x += a0; o.y += a1; o.z += a2; o.w += a3;
  *(float4*)(out + (size_t)bc * NN + pos) = o;
}

extern "C" void kernel_launch(void* const* d_in, const int* in_sizes, int n_in,
                              void* d_out, int out_size, void* d_ws, size_t ws_size,
                              hipStream_t stream) {
  const float* x = (const float*)d_in[0];
  const float* Wqk = (const float*)d_in[1];
  const float* bqk = (const float*)d_in[2];
  const float* lw = (const float*)d_in[3];
  const float* lb = (const float*)d_in[4];
  float* out = (float*)d_out;
  char* ws = (char*)d_ws;
  // ws layout (≈189 MB peak; kmean partials overlay the kvp region, which is
  // only live from kv_mfma_k onward; kvtb overlays old kv slot). xtb for ALL
  // batches lives in d_out (75.5 MB <= 151 MB), free until out_mfma_k.
  unsigned short* qbf = (unsigned short*)(ws);                 // 75,497,472 B
  unsigned short* kbf = (unsigned short*)(ws + 75497472);      // 75,497,472 B
  float* rope = (float*)(ws + 150994944);                      //    196,608 B
  float* kmean = (float*)(ws + 151191552);                     //     16,384 B
  float* z = (float*)(ws + 151207936);                         //  1,179,648 B
  float* kvp = (float*)(ws + 152387584);                       // 33,554,432 B
  float* kmean_part = (float*)(ws + 152387584 + 16777216);     //    294,912 B (overlay)
  unsigned short* kvtb = (unsigned short*)(ws + 185942016);    //  1,048,576 B
  unsigned short* Wbf = (unsigned short*)(ws + 188039168);     //  1,048,576 B
  unsigned short* xtb = (unsigned short*)d_out;                // 75,497,472 B (scratch in out)

  conv_w_k<<<dim3(512), dim3(256), 0, stream>>>(Wqk, Wbf);
  rope_table_k<<<dim3(96), dim3(256), 0, stream>>>(rope);
  transpose_all_k<<<dim3(144, 8, 8), dim3(256), 0, stream>>>(x, xtb);
  gemm_qk_mfma<<<dim3(8, 72, 8), dim3(256), 0, stream>>>(xtb, Wbf, bqk, qbf, kbf);
  kmean_p1_k<<<dim3(18, 32), dim3(256), 0, stream>>>(kbf, kmean_part);
  kmean_p2_k<<<dim3(16), dim3(256), 0, stream>>>(kmean_part, kmean);
  z_k<<<dim3(9216), dim3(256), 0, stream>>>(qbf, kmean, z);
  kv_mfma_k<<<dim3(16, 32), dim3(256), 0, stream>>>(kbf, x, rope, kvp);
  kv_reduce_k<<<dim3(2048), dim3(256), 0, stream>>>(kvp, kvtb);
  out_mfma_k<<<dim3(72, 32), dim3(256), 0, stream>>>(qbf, kvtb, z, rope, out);
  lepe_k<<<dim3(36864), dim3(256), 0, stream>>>(x, lw, lb, out);
}

// Round 4
// 723.186 us; speedup vs baseline: 1.2810x; 1.0180x over previous
//
#include <hip/hip_runtime.h>
#include <hip/hip_bf16.h>
#include <cstdint>

// Problem constants
#define BB 8
#define CC 512
#define HH 96
#define NN 9216      // 96*96
#define HEADS 4
#define HD 128
#define KMAX 256     // c/2

typedef unsigned short ushort_t;
typedef __attribute__((ext_vector_type(8))) short bf16x8;
typedef __attribute__((ext_vector_type(4))) float f32x4;

__device__ __forceinline__ unsigned short f2bf(float f) {
  unsigned int u = __float_as_uint(f);
  u += 0x7fffu + ((u >> 16) & 1u);   // RNE; values are finite here
  return (unsigned short)(u >> 16);
}
__device__ __forceinline__ float bf2f(unsigned short s) {
  return __uint_as_float(((unsigned int)s) << 16);
}
__device__ __forceinline__ unsigned int pk2(float lo, float hi) {
  return (unsigned int)f2bf(lo) | ((unsigned int)f2bf(hi) << 16);
}

// async global->LDS 16B: lds dest must be wave-uniform base; HW scatters lane i at +16*i
__device__ __forceinline__ void gld16(const void* g, void* l) {
  __builtin_amdgcn_global_load_lds(
      (const __attribute__((address_space(1))) unsigned int*)(uintptr_t)g,
      (__attribute__((address_space(3))) unsigned int*)(unsigned int)(uintptr_t)l,
      16, 0, 0);
}

// ---------------- rope table: cos/sin[col][kk], col = pos % 96 ----------------
__global__ void rope_table_k(float* __restrict__ rope) {
  int t = blockIdx.x * 256 + threadIdx.x;
  if (t >= HH * KMAX) return;
  int col = t >> 8;
  int kk = t & (KMAX - 1);
  float theta = powf(10000.0f, -((float)kk) / (float)KMAX);
  float ang = (float)col * theta;
  float s, c;
  sincosf(ang, &s, &c);
  rope[2 * t] = c;
  rope[2 * t + 1] = s;
}

// ---------------- W fp32 -> bf16 ----------------------------------------------
__global__ void conv_w_k(const float* __restrict__ W, unsigned short* __restrict__ Wbf) {
  int t = blockIdx.x * 256 + threadIdx.x;  // 131072 float4s
  float4 v = *(const float4*)(W + (size_t)t * 4);
  unsigned int lo = (unsigned int)f2bf(v.x) | ((unsigned int)f2bf(v.y) << 16);
  unsigned int hi = (unsigned int)f2bf(v.z) | ((unsigned int)f2bf(v.w) << 16);
  *(uint2*)(Wbf + (size_t)t * 4) = make_uint2(lo, hi);
}

// ------- all-batch transpose: x[b][ch][pos] fp32 -> xt[b][pos][ch] bf16 -------
__global__ void transpose_all_k(const float* __restrict__ x, unsigned short* __restrict__ xt) {
  __shared__ unsigned short T[64 * 72];  // [pos][ch], pad 8 (row 144B, 16B-aligned)
  const int pos0 = blockIdx.x * 64;
  const int ch0 = blockIdx.y * 64;
  const int b = blockIdx.z;
  const int tid = threadIdx.x;
#pragma unroll
  for (int i = 0; i < 4; ++i) {
    int fi = i * 256 + tid;          // 0..1023
    int ch = fi >> 4, p4 = fi & 15;  // 64 ch x 16 float4
    float4 v = *(const float4*)(x + ((size_t)b * CC + ch0 + ch) * NN + pos0 + p4 * 4);
    T[(p4 * 4 + 0) * 72 + ch] = f2bf(v.x);
    T[(p4 * 4 + 1) * 72 + ch] = f2bf(v.y);
    T[(p4 * 4 + 2) * 72 + ch] = f2bf(v.z);
    T[(p4 * 4 + 3) * 72 + ch] = f2bf(v.w);
  }
  __syncthreads();
#pragma unroll
  for (int i = 0; i < 2; ++i) {
    int s = i * 256 + tid;          // 0..511
    int p = s >> 3, cc = s & 7;     // 64 rows x 8 chunks of 16B
    uint4 u = *(const uint4*)&T[p * 72 + cc * 8];
    *(uint4*)(xt + ((size_t)b * NN + pos0 + p) * CC + ch0 + cc * 8) = u;
  }
}

// ---------------- qk GEMM (MFMA bf16): C[m,j] = sum_ch xt[m,ch]*Wbf[j,ch] ------
// One dispatch, 1D grid 4608 with XCD-grouping swizzle: flat = 64A + 8B + C
// (A=0..71, B,C=0..7) decodes to g = 8A + C (A-tile id: b*? no -> b=g/72? see
// below), bn = B. The 8 bn-blocks sharing an A-tile all have flat%8 == C ->
// same XCD and back-to-back -> A fetched once per XCD, 7/8 L2-hit.
__launch_bounds__(256)
__global__ void gemm_qk_mfma(const unsigned short* __restrict__ xtall,
                             const unsigned short* __restrict__ Wbf,
                             const float* __restrict__ bqk,
                             unsigned short* __restrict__ qout,
                             unsigned short* __restrict__ kout) {
  __shared__ __align__(16) unsigned short sA[128 * 64];
  __shared__ __align__(16) unsigned short sB[128 * 64];
  const int flat = blockIdx.x;                 // 0..4607
  const int bn = (flat >> 3) & 7;              // j block 0..7
  const int g = ((flat >> 6) << 3) | (flat & 7);  // A-tile id 0..575
  const int b = g / 72;
  const int m0 = (g - b * 72) * 128;           // pos within batch
  const int tid = threadIdx.x;
  const int wv = tid >> 6, lane = tid & 63;
  const int j0 = bn * 128;
  const unsigned short* xt = xtall + (size_t)b * NN * CC;
  const int row = lane & 15, quad = lane >> 4;
  const int mt0 = (wv & 1) * 64, nt0 = (wv >> 1) * 64;
  f32x4 acc[4][4];
#pragma unroll
  for (int mi = 0; mi < 4; ++mi)
#pragma unroll
    for (int ni = 0; ni < 4; ++ni) acc[mi][ni] = (f32x4){0.f, 0.f, 0.f, 0.f};

  for (int kt = 0; kt < CC; kt += 64) {
#pragma unroll
    for (int it = 0; it < 4; ++it) {
      int s = it * 256 + tid;                 // LDS slot (16B units)
      int srow = s >> 3;                      // tile row 0..127
      int sc = (s & 7) ^ (srow & 7);          // swizzled chunk -> global chunk
      int ldsoff = (it * 256 + wv * 64) * 8;  // wave-uniform base (ushort units)
      gld16(xt + (size_t)(m0 + srow) * CC + kt + sc * 8, &sA[ldsoff]);
      gld16(Wbf + (size_t)(j0 + srow) * CC + kt + sc * 8, &sB[ldsoff]);
    }
    __syncthreads();
#pragma unroll
    for (int ks = 0; ks < 2; ++ks) {
      bf16x8 af[4], bf[4];
      const int chunk = (ks * 4 + quad) ^ (row & 7);
#pragma unroll
      for (int mi = 0; mi < 4; ++mi)
        af[mi] = *(const bf16x8*)&sA[((mt0 + mi * 16 + row) * 8 + chunk) * 8];
#pragma unroll
      for (int ni = 0; ni < 4; ++ni)
        bf[ni] = *(const bf16x8*)&sB[((nt0 + ni * 16 + row) * 8 + chunk) * 8];
#pragma unroll
      for (int mi = 0; mi < 4; ++mi)
#pragma unroll
        for (int ni = 0; ni < 4; ++ni)
          acc[mi][ni] = __builtin_amdgcn_mfma_f32_16x16x32_bf16(af[mi], bf[ni], acc[mi][ni], 0, 0, 0);
    }
    __syncthreads();
  }
  // epilogue: bias + elu+1, bf16 store. C/D layout: col=lane&15, row=quad*4+reg.
  unsigned short* dst = (j0 < CC) ? qout : kout;
  const int jl = (j0 & (CC - 1)) + nt0;
  float bj[4];
#pragma unroll
  for (int ni = 0; ni < 4; ++ni) bj[ni] = bqk[j0 + nt0 + ni * 16 + row];
#pragma unroll
  for (int mi = 0; mi < 4; ++mi) {
#pragma unroll
    for (int ni = 0; ni < 4; ++ni) {
#pragma unroll
      for (int r = 0; r < 4; ++r) {
        float v = acc[mi][ni][r] + bj[ni];
        v = v > 0.f ? v + 1.f : expm1f(v) + 1.f;
        int mrow = m0 + mt0 + mi * 16 + quad * 4 + r;
        dst[((size_t)b * NN + mrow) * CC + jl + ni * 16 + row] = f2bf(v);
      }
    }
  }
}

// ---------------- k_mean 2-stage over weird flat reshape ----------------------
__global__ void kmean_p1_k(const unsigned short* __restrict__ kbf, float* __restrict__ part) {
  __shared__ float red[256];
  const int seg = blockIdx.x;  // 0..17
  const int bh = blockIdx.y;   // 0..31
  const int b = bh >> 2, head = bh & 3;
  const int tid = threadIdx.x;
  const int d = tid & 127, half = tid >> 7;
  const unsigned short* base =
      kbf + ((size_t)b * NN + head * 2304 + seg * 128 + half * 64) * CC + d;
  float sum = 0.f;
  for (int pp = 0; pp < 64; ++pp) {
    const unsigned short* rp = base + (size_t)pp * CC;
    sum += bf2f(rp[0]) + bf2f(rp[128]) + bf2f(rp[256]) + bf2f(rp[384]);
  }
  red[tid] = sum;
  __syncthreads();
  if (half == 0) part[((size_t)bh * 18 + seg) * 128 + d] = red[d] + red[d + 128];
}

__global__ void kmean_p2_k(const float* __restrict__ part, float* __restrict__ kmean) {
  int idx = blockIdx.x * 256 + threadIdx.x;  // 4096
  int bh = idx >> 7, d = idx & 127;
  float s = 0.f;
#pragma unroll
  for (int i = 0; i < 18; ++i) s += part[((size_t)bh * 18 + i) * 128 + d];
  kmean[idx] = s * (1.0f / 9216.0f);
}

// ---------------- z[bh,p] = 1/(q2[bh,p,:].kmean[bh,:] + 1e-6) -----------------
__global__ void z_k(const unsigned short* __restrict__ qbf, const float* __restrict__ kmean,
                    float* __restrict__ z) {
  const int wv = threadIdx.x >> 6, lane = threadIdx.x & 63;
  const int zbase = (blockIdx.x * 4 + wv) * 8;
  const int bh = zbase / NN;
  const int p0 = zbase % NN;
  const int b = bh >> 2, head = bh & 3;
  const float km0 = kmean[bh * 128 + lane * 2];
  const float km1 = kmean[bh * 128 + lane * 2 + 1];
#pragma unroll
  for (int it = 0; it < 8; ++it) {
    const int p = p0 + it;
    const int pos = head * 2304 + (p >> 2);
    const int chb = (p & 3) * 128;
    const unsigned short* qp = qbf + ((size_t)b * NN + pos) * CC + chb + lane * 2;
    float dot = bf2f(qp[0]) * km0 + bf2f(qp[1]) * km1;
#pragma unroll
    for (int off = 1; off < 64; off <<= 1) dot += __shfl_xor(dot, off, 64);
    if (lane == 0) z[zbase + it] = 1.0f / (dot + 1e-6f);
  }
}

// ---------------- kv partials via MFMA ----------------------------------------
// kvp[s][bh][e][d] = sum_{q in seg} V[q][e] * Krope[q][d]
// q-order: q = r*2304 + t with p = 4t + r, so V[q][e] = x[b, r*128+e, head*2304+t]
// is k-contiguous (global-direct A frags, cvt fp32->bf16). Krope is built in
// registers from kbf rows (each thread owns 4 output d-rows x 8 q: the rope
// pair (re,im) IS two d-rows, so the transpose is free), then ds_write_b128
// into octet-swizzled sK[d][q] for conflict-free b128 B-frag reads.
__launch_bounds__(256, 2)
__global__ void kv_mfma_k(const unsigned short* __restrict__ kbf, const float* __restrict__ x,
                          const float* __restrict__ rope, float* __restrict__ kvp) {
  __shared__ __align__(16) unsigned short sK[128 * 64];  // [d 128][q 64], swizzled octets
  const int s = blockIdx.x;   // 0..15 (q segment)
  const int bh = blockIdx.y;  // 0..31
  const int b = bh >> 2, head = bh & 3;
  const int tid = threadIdx.x;
  const int wv = tid >> 6, lane = tid & 63;
  const int row = lane & 15, quad = lane >> 4;
  const int e0 = (wv & 1) * 64, d0 = (wv >> 1) * 64;
  const int r = s >> 2;           // p = 4t + r
  const int t0 = (s & 3) * 576;   // t range [t0, t0+576), 9 chunks of 64

  // staging role: this thread owns q-octet qg (8 q) x 4 d-rows (2 rope pairs)
  const int qg = tid & 7;
  const int dg = (tid >> 3) * 4;  // first d row (0,4,..,124)
  const unsigned short* kbase = kbf + (size_t)b * NN * CC + head * HD + dg;
  const int pairb = head * 64 + (dg >> 1);

  f32x4 acc[4][4];
#pragma unroll
  for (int mi = 0; mi < 4; ++mi)
#pragma unroll
    for (int ni = 0; ni < 4; ++ni) acc[mi][ni] = (f32x4){0.f, 0.f, 0.f, 0.f};

  for (int ck = 0; ck < 9; ++ck) {
    const int tc = t0 + ck * 64;
    // ---- issue V (A-operand) global loads early: 8 frags x 32B fp32 ----
    float4 a0[8], a1[8];
#pragma unroll
    for (int mi = 0; mi < 4; ++mi)
#pragma unroll
      for (int ks = 0; ks < 2; ++ks) {
        const float* xp = x + (size_t)(b * CC + r * 128 + e0 + mi * 16 + row) * NN +
                          head * 2304 + tc + ks * 32 + quad * 8;
        a0[mi * 2 + ks] = *(const float4*)xp;
        a1[mi * 2 + ks] = *(const float4*)(xp + 4);
      }
    // ---- K staging: rope in fp32, transpose-by-ownership, 4 b128 writes ----
    {
      int p = 4 * (tc + qg * 8) + r;
      int col = p % 96;
      float rw0[8], rw1[8], rw2[8], rw3[8];
#pragma unroll
      for (int j = 0; j < 8; ++j) {
        uint2 kv2 = *(const uint2*)(kbase + (size_t)p * CC);
        const float* rp = rope + ((size_t)col * KMAX + pairb) * 2;
        float4 cs = *(const float4*)rp;  // c0 s0 c1 s1
        float re0 = bf2f((unsigned short)(kv2.x & 0xffffu));
        float im0 = bf2f((unsigned short)(kv2.x >> 16));
        float re1 = bf2f((unsigned short)(kv2.y & 0xffffu));
        float im1 = bf2f((unsigned short)(kv2.y >> 16));
        rw0[j] = cs.x * re0 - cs.y * im0;
        rw1[j] = cs.y * re0 + cs.x * im0;
        rw2[j] = cs.z * re1 - cs.w * im1;
        rw3[j] = cs.w * re1 + cs.z * im1;
        p += 4;
        col += 4;
        col = (col >= 96) ? col - 96 : col;
      }
#pragma unroll
      for (int rr = 0; rr < 4; ++rr) {
        const float* rw = (rr == 0) ? rw0 : (rr == 1) ? rw1 : (rr == 2) ? rw2 : rw3;
        const int d = dg + rr;
        uint4 pk;
        pk.x = pk2(rw[0], rw[1]);
        pk.y = pk2(rw[2], rw[3]);
        pk.z = pk2(rw[4], rw[5]);
        pk.w = pk2(rw[6], rw[7]);
        *(uint4*)&sK[(d * 8 + (qg ^ (d & 7))) * 8] = pk;
      }
    }
    __syncthreads();
    // ---- MFMA phase ----
#pragma unroll
    for (int ks = 0; ks < 2; ++ks) {
      bf16x8 bfr[4];
#pragma unroll
      for (int ni = 0; ni < 4; ++ni) {
        const int d = d0 + ni * 16 + row;
        const int o = (ks * 4 + quad) ^ (d & 7);
        bfr[ni] = *(const bf16x8*)&sK[(d * 8 + o) * 8];
      }
#pragma unroll
      for (int mi = 0; mi < 4; ++mi) {
        const int f = mi * 2 + ks;
        union { bf16x8 v; unsigned int u[4]; } af;
        af.u[0] = pk2(a0[f].x, a0[f].y);
        af.u[1] = pk2(a0[f].z, a0[f].w);
        af.u[2] = pk2(a1[f].x, a1[f].y);
        af.u[3] = pk2(a1[f].z, a1[f].w);
#pragma unroll
        for (int ni = 0; ni < 4; ++ni)
          acc[mi][ni] = __builtin_amdgcn_mfma_f32_16x16x32_bf16(af.v, bfr[ni], acc[mi][ni], 0, 0, 0);
      }
    }
    __syncthreads();  // protect sK before next chunk's writes
  }
  // epilogue: D layout col(n=d)=lane&15, row(m=e)=quad*4+reg -> kvp[e][d]
  float* dst = kvp + (size_t)(s * 32 + bh) * (HD * HD);
#pragma unroll
  for (int mi = 0; mi < 4; ++mi) {
#pragma unroll
    for (int ni = 0; ni < 4; ++ni) {
#pragma unroll
      for (int rr = 0; rr < 4; ++rr) {
        const int e = e0 + mi * 16 + quad * 4 + rr;
        const int d = d0 + ni * 16 + row;
        dst[e * HD + d] = acc[mi][ni][rr];
      }
    }
  }
}

// ---------------- kv reduce: sum partials (already [e][d]), emit bf16 ---------
__global__ void kv_reduce_k(const float* __restrict__ kvp, unsigned short* __restrict__ kvtb) {
  int idx = blockIdx.x * 256 + threadIdx.x;  // 524288 = 32*128*128
  float ssum = 0.f;
#pragma unroll
  for (int i = 0; i < 16; ++i) ssum += kvp[(size_t)i * (32 * HD * HD) + idx];
  kvtb[idx] = f2bf(ssum * (1.0f / 9216.0f));
}

// ---------------- out (MFMA): out[b, head*128+e, pos] = z * sum_d qrope*kv ----
// m = e (A from kvtb[bh][e][d], k-contig), n = pos (B from rope(q), k-contig).
// No LDS; A/B frags read straight from global (kvtb is 1 MB, L2/L3-hot).
__launch_bounds__(256)
__global__ void out_mfma_k(const unsigned short* __restrict__ qbf,
                           const unsigned short* __restrict__ kvtb,
                           const float* __restrict__ z, const float* __restrict__ rope,
                           float* __restrict__ out) {
  const int bh = blockIdx.y, b = bh >> 2, head = bh & 3;
  const int pos0 = blockIdx.x * 128;
  const int tid = threadIdx.x, wv = tid >> 6, lane = tid & 63;
  const int row = lane & 15, quad = lane >> 4;
  const int e0 = (wv & 1) * 64;
  const int p0 = (wv >> 1) * 64;
  f32x4 acc[4][4];
#pragma unroll
  for (int mi = 0; mi < 4; ++mi)
#pragma unroll
    for (int ni = 0; ni < 4; ++ni) acc[mi][ni] = (f32x4){0.f, 0.f, 0.f, 0.f};

  int posn[4], coln[4];
#pragma unroll
  for (int ni = 0; ni < 4; ++ni) {
    posn[ni] = pos0 + p0 + ni * 16 + row;
    coln[ni] = posn[ni] % 96;
  }

#pragma unroll
  for (int kt = 0; kt < HD; kt += 32) {
    bf16x8 af[4], bfr[4];
#pragma unroll
    for (int mi = 0; mi < 4; ++mi)
      af[mi] = *(const bf16x8*)&kvtb[((size_t)bh * HD + e0 + mi * 16 + row) * HD + kt + quad * 8];
#pragma unroll
    for (int ni = 0; ni < 4; ++ni) {
      const uint4 u = *(const uint4*)(qbf + ((size_t)b * NN + posn[ni]) * CC +
                                      head * HD + kt + quad * 8);
      const int pairb = head * 64 + (kt >> 1) + quad * 4;
      const float* rp = rope + ((size_t)coln[ni] * KMAX + pairb) * 2;
      float4 r0 = *(const float4*)rp;        // c0 s0 c1 s1
      float4 r1 = *(const float4*)(rp + 4);  // c2 s2 c3 s3
      unsigned int uu[4] = {u.x, u.y, u.z, u.w};
      float cs[8] = {r0.x, r0.y, r0.z, r0.w, r1.x, r1.y, r1.z, r1.w};
      bf16x8 bb;
#pragma unroll
      for (int pr = 0; pr < 4; ++pr) {
        float re = bf2f((unsigned short)(uu[pr] & 0xffffu));
        float im = bf2f((unsigned short)(uu[pr] >> 16));
        float c = cs[2 * pr], s = cs[2 * pr + 1];
        bb[2 * pr] = (short)f2bf(c * re - s * im);
        bb[2 * pr + 1] = (short)f2bf(s * re + c * im);
      }
      bfr[ni] = bb;
    }
#pragma unroll
    for (int mi = 0; mi < 4; ++mi)
#pragma unroll
      for (int ni = 0; ni < 4; ++ni)
        acc[mi][ni] = __builtin_amdgcn_mfma_f32_16x16x32_bf16(af[mi], bfr[ni], acc[mi][ni], 0, 0, 0);
  }
  float zv[4];
#pragma unroll
  for (int ni = 0; ni < 4; ++ni) zv[ni] = z[(size_t)bh * NN + posn[ni]];
#pragma unroll
  for (int mi = 0; mi < 4; ++mi) {
#pragma unroll
    for (int ni = 0; ni < 4; ++ni) {
#pragma unroll
      for (int r = 0; r < 4; ++r) {
        int e = e0 + mi * 16 + quad * 4 + r;
        out[((size_t)b * CC + head * HD + e) * NN + posn[ni]] = acc[mi][ni][r] * zv[ni];
      }
    }
  }
}

// ---------------- lepe: depthwise 3x3 conv of x, ADDS into d_out --------------
// ILP-oriented: per thread 4 outputs from 3 rows x (float4 + 2 edge scalars);
// round-2 version was latency-bound at VGPR=8 (36 dependent scalar loads).
__global__ void lepe_k(const float* __restrict__ x, const float* __restrict__ lw,
                       const float* __restrict__ lb, float* __restrict__ out) {
  const int blk = blockIdx.x;  // B*C*9
  const int bc = blk / 9;
  const int tile = blk - bc * 9;
  const int ch = bc & (CC - 1);
  const float* wp = lw + ch * 9;
  float w[9];
#pragma unroll
  for (int t = 0; t < 9; ++t) w[t] = wp[t];
  const float bias = lb[ch];
  const float* xp = x + (size_t)bc * NN;
  const int pos = tile * 1024 + threadIdx.x * 4;
  const int pi = pos / 96;
  const int pj = pos - pi * 96;  // multiple of 4

  float4 o = *(const float4*)(out + (size_t)bc * NN + pos);  // RMW read early

  float a0 = bias, a1 = bias, a2 = bias, a3 = bias;
#pragma unroll
  for (int r = 0; r < 3; ++r) {
    const int y = pi + r - 1;
    if ((unsigned)y >= 96u) continue;
    const float* rowp = xp + y * 96 + pj;
    float4 M = *(const float4*)rowp;
    float Lv = (pj > 0) ? rowp[-1] : 0.f;
    float Rv = (pj < 92) ? rowp[4] : 0.f;
    const float w0 = w[r * 3 + 0], w1 = w[r * 3 + 1], w2 = w[r * 3 + 2];
    a0 += w0 * Lv + w1 * M.x + w2 * M.y;
    a1 += w0 * M.x + w1 * M.y + w2 * M.z;
    a2 += w0 * M.y + w1 * M.z + w2 * M.w;
    a3 += w0 * M.z + w1 * M.w + w2 * Rv;
  }
  o.x += a0; o.y += a1; o.z += a2; o.w += a3;
  *(float4*)(out + (size_t)bc * NN + pos) = o;
}

extern "C" void kernel_launch(void* const* d_in, const int* in_sizes, int n_in,
                              void* d_out, int out_size, void* d_ws, size_t ws_size,
                              hipStream_t stream) {
  const float* x = (const float*)d_in[0];
  const float* Wqk = (const float*)d_in[1];
  const float* bqk = (const float*)d_in[2];
  const float* lw = (const float*)d_in[3];
  const float* lb = (const float*)d_in[4];
  float* out = (float*)d_out;
  char* ws = (char*)d_ws;
  // ws layout (≈189 MB peak; kmean partials overlay the kvp region, which is
  // only live from kv_mfma_k onward; kvtb overlays old kv slot). xtb for ALL
  // batches lives in d_out (75.5 MB <= 151 MB), free until out_mfma_k.
  unsigned short* qbf = (unsigned short*)(ws);                 // 75,497,472 B
  unsigned short* kbf = (unsigned short*)(ws + 75497472);      // 75,497,472 B
  float* rope = (float*)(ws + 150994944);                      //    196,608 B
  float* kmean = (float*)(ws + 151191552);                     //     16,384 B
  float* z = (float*)(ws + 151207936);                         //  1,179,648 B
  float* kvp = (float*)(ws + 152387584);                       // 33,554,432 B
  float* kmean_part = (float*)(ws + 152387584 + 16777216);     //    294,912 B (overlay)
  unsigned short* kvtb = (unsigned short*)(ws + 185942016);    //  1,048,576 B
  unsigned short* Wbf = (unsigned short*)(ws + 188039168);     //  1,048,576 B
  unsigned short* xtb = (unsigned short*)d_out;                // 75,497,472 B (scratch in out)

  conv_w_k<<<dim3(512), dim3(256), 0, stream>>>(Wqk, Wbf);
  rope_table_k<<<dim3(96), dim3(256), 0, stream>>>(rope);
  transpose_all_k<<<dim3(144, 8, 8), dim3(256), 0, stream>>>(x, xtb);
  gemm_qk_mfma<<<dim3(4608), dim3(256), 0, stream>>>(xtb, Wbf, bqk, qbf, kbf);
  kmean_p1_k<<<dim3(18, 32), dim3(256), 0, stream>>>(kbf, kmean_part);
  kmean_p2_k<<<dim3(16), dim3(256), 0, stream>>>(kmean_part, kmean);
  z_k<<<dim3(9216), dim3(256), 0, stream>>>(qbf, kmean, z);
  kv_mfma_k<<<dim3(16, 32), dim3(256), 0, stream>>>(kbf, x, rope, kvp);
  kv_reduce_k<<<dim3(2048), dim3(256), 0, stream>>>(kvp, kvtb);
  out_mfma_k<<<dim3(72, 32), dim3(256), 0, stream>>>(qbf, kvtb, z, rope, out);
  lepe_k<<<dim3(36864), dim3(256), 0, stream>>>(x, lw, lb, out);
}

// Round 5
// 713.248 us; speedup vs baseline: 1.2988x; 1.0139x over previous
//
#include <hip/hip_runtime.h>
#include <hip/hip_bf16.h>
#include <cstdint>

// Problem constants
#define BB 8
#define CC 512
#define HH 96
#define NN 9216      // 96*96
#define HEADS 4
#define HD 128
#define KMAX 256     // c/2

typedef unsigned short ushort_t;
typedef __attribute__((ext_vector_type(8))) short bf16x8;
typedef __attribute__((ext_vector_type(4))) float f32x4;

__device__ __forceinline__ unsigned short f2bf(float f) {
  unsigned int u = __float_as_uint(f);
  u += 0x7fffu + ((u >> 16) & 1u);   // RNE; values are finite here
  return (unsigned short)(u >> 16);
}
__device__ __forceinline__ float bf2f(unsigned short s) {
  return __uint_as_float(((unsigned int)s) << 16);
}
__device__ __forceinline__ unsigned int pk2(float lo, float hi) {
  return (unsigned int)f2bf(lo) | ((unsigned int)f2bf(hi) << 16);
}

// async global->LDS 16B: lds dest must be wave-uniform base; HW scatters lane i at +16*i
__device__ __forceinline__ void gld16(const void* g, void* l) {
  __builtin_amdgcn_global_load_lds(
      (const __attribute__((address_space(1))) unsigned int*)(uintptr_t)g,
      (__attribute__((address_space(3))) unsigned int*)(unsigned int)(uintptr_t)l,
      16, 0, 0);
}

// ---------------- rope table: cos/sin[col][kk], col = pos % 96 ----------------
__global__ void rope_table_k(float* __restrict__ rope) {
  int t = blockIdx.x * 256 + threadIdx.x;
  if (t >= HH * KMAX) return;
  int col = t >> 8;
  int kk = t & (KMAX - 1);
  float theta = powf(10000.0f, -((float)kk) / (float)KMAX);
  float ang = (float)col * theta;
  float s, c;
  sincosf(ang, &s, &c);
  rope[2 * t] = c;
  rope[2 * t + 1] = s;
}

// ---------------- W fp32 -> bf16 ----------------------------------------------
__global__ void conv_w_k(const float* __restrict__ W, unsigned short* __restrict__ Wbf) {
  int t = blockIdx.x * 256 + threadIdx.x;  // 131072 float4s
  float4 v = *(const float4*)(W + (size_t)t * 4);
  unsigned int lo = (unsigned int)f2bf(v.x) | ((unsigned int)f2bf(v.y) << 16);
  unsigned int hi = (unsigned int)f2bf(v.z) | ((unsigned int)f2bf(v.w) << 16);
  *(uint2*)(Wbf + (size_t)t * 4) = make_uint2(lo, hi);
}

// ------- all-batch transpose: x[b][ch][pos] fp32 -> xt[b][pos][ch] bf16 -------
__global__ void transpose_all_k(const float* __restrict__ x, unsigned short* __restrict__ xt) {
  __shared__ unsigned short T[64 * 72];  // [pos][ch], pad 8 (row 144B, 16B-aligned)
  const int pos0 = blockIdx.x * 64;
  const int ch0 = blockIdx.y * 64;
  const int b = blockIdx.z;
  const int tid = threadIdx.x;
#pragma unroll
  for (int i = 0; i < 4; ++i) {
    int fi = i * 256 + tid;          // 0..1023
    int ch = fi >> 4, p4 = fi & 15;  // 64 ch x 16 float4
    float4 v = *(const float4*)(x + ((size_t)b * CC + ch0 + ch) * NN + pos0 + p4 * 4);
    T[(p4 * 4 + 0) * 72 + ch] = f2bf(v.x);
    T[(p4 * 4 + 1) * 72 + ch] = f2bf(v.y);
    T[(p4 * 4 + 2) * 72 + ch] = f2bf(v.z);
    T[(p4 * 4 + 3) * 72 + ch] = f2bf(v.w);
  }
  __syncthreads();
#pragma unroll
  for (int i = 0; i < 2; ++i) {
    int s = i * 256 + tid;          // 0..511
    int p = s >> 3, cc = s & 7;     // 64 rows x 8 chunks of 16B
    uint4 u = *(const uint4*)&T[p * 72 + cc * 8];
    *(uint4*)(xt + ((size_t)b * NN + pos0 + p) * CC + ch0 + cc * 8) = u;
  }
}

// ---------------- qk GEMM (MFMA bf16) -----------------------------------------
// Swapped-operand MFMA: A = W-frags (j dim), B = xt-frags (pos dim) so that
// D reg-dim = 4 CONSECUTIVE j -> uint2-packed stores (16 insts vs 64 scalar).
// elu+1 computed as exp(v) for v<=0 (identical function, 1 VALU op).
// k-half blocks also fold the k column-sum (per pos-quarter) via shuffle-reduce
// + atomicAdd into ksum[b][pq][jk] -- replaces the kmean_p1/p2 kernels.
// XCD-grouping 1D swizzle as before.
__launch_bounds__(256)
__global__ void gemm_qk_mfma(const unsigned short* __restrict__ xtall,
                             const unsigned short* __restrict__ Wbf,
                             const float* __restrict__ bqk,
                             unsigned short* __restrict__ qout,
                             unsigned short* __restrict__ kout,
                             float* __restrict__ ksum) {
  __shared__ __align__(16) unsigned short sA[128 * 64];
  __shared__ __align__(16) unsigned short sB[128 * 64];
  const int flat = blockIdx.x;                    // 0..4607
  const int bn = (flat >> 3) & 7;                 // j block 0..7
  const int g = ((flat >> 6) << 3) | (flat & 7);  // A-tile id 0..575
  const int b = g / 72;
  const int m0 = (g - b * 72) * 128;              // pos within batch
  const int tid = threadIdx.x;
  const int wv = tid >> 6, lane = tid & 63;
  const int j0 = bn * 128;
  const unsigned short* xt = xtall + (size_t)b * NN * CC;
  const int row = lane & 15, quad = lane >> 4;
  const int jt0 = (wv & 1) * 64, pt0 = (wv >> 1) * 64;
  f32x4 acc[4][4];  // [ji][pi]
#pragma unroll
  for (int ji = 0; ji < 4; ++ji)
#pragma unroll
    for (int pi = 0; pi < 4; ++pi) acc[ji][pi] = (f32x4){0.f, 0.f, 0.f, 0.f};

  for (int kt = 0; kt < CC; kt += 64) {
#pragma unroll
    for (int it = 0; it < 4; ++it) {
      int s = it * 256 + tid;                 // LDS slot (16B units)
      int srow = s >> 3;                      // tile row 0..127
      int sc = (s & 7) ^ (srow & 7);          // swizzled chunk -> global chunk
      int ldsoff = (it * 256 + wv * 64) * 8;  // wave-uniform base (ushort units)
      gld16(xt + (size_t)(m0 + srow) * CC + kt + sc * 8, &sA[ldsoff]);
      gld16(Wbf + (size_t)(j0 + srow) * CC + kt + sc * 8, &sB[ldsoff]);
    }
    __syncthreads();
#pragma unroll
    for (int ks = 0; ks < 2; ++ks) {
      bf16x8 aw[4], ax[4];
      const int chunk = (ks * 4 + quad) ^ (row & 7);
#pragma unroll
      for (int ji = 0; ji < 4; ++ji)
        aw[ji] = *(const bf16x8*)&sB[((jt0 + ji * 16 + row) * 8 + chunk) * 8];
#pragma unroll
      for (int pi = 0; pi < 4; ++pi)
        ax[pi] = *(const bf16x8*)&sA[((pt0 + pi * 16 + row) * 8 + chunk) * 8];
#pragma unroll
      for (int ji = 0; ji < 4; ++ji)
#pragma unroll
        for (int pi = 0; pi < 4; ++pi)
          acc[ji][pi] = __builtin_amdgcn_mfma_f32_16x16x32_bf16(aw[ji], ax[pi], acc[ji][pi], 0, 0, 0);
    }
    __syncthreads();
  }
  // epilogue: D layout: j = jt0 + ji*16 + quad*4 + r, pos = pt0 + pi*16 + row.
  unsigned short* dst = (j0 < CC) ? qout : kout;
  const int jl0 = j0 & (CC - 1);
  const int pq = (m0 >> 7) / 18;  // pos-quarter (2304 = 18*128)
#pragma unroll
  for (int ji = 0; ji < 4; ++ji) {
    const float4 bb = *(const float4*)&bqk[j0 + jt0 + ji * 16 + quad * 4];
    const float bj[4] = {bb.x, bb.y, bb.z, bb.w};
    float sacc[4] = {0.f, 0.f, 0.f, 0.f};
#pragma unroll
    for (int pi = 0; pi < 4; ++pi) {
      float v[4];
#pragma unroll
      for (int r = 0; r < 4; ++r) {
        float t = acc[ji][pi][r] + bj[r];
        v[r] = t > 0.f ? t + 1.f : __expf(t);   // elu(t)+1 == exp(t) for t<=0
        sacc[r] += v[r];
      }
      const int posm = m0 + pt0 + pi * 16 + row;
      uint2 pkd = make_uint2(pk2(v[0], v[1]), pk2(v[2], v[3]));
      *(uint2*)&dst[((size_t)b * NN + posm) * CC + jl0 + jt0 + ji * 16 + quad * 4] = pkd;
    }
    if (j0 >= CC) {  // k-half: fold column sums (this wave covers 64 pos)
#pragma unroll
      for (int r = 0; r < 4; ++r) {
        float s = sacc[r];
        s += __shfl_xor(s, 1);
        s += __shfl_xor(s, 2);
        s += __shfl_xor(s, 4);
        s += __shfl_xor(s, 8);
        if (row == 0)
          atomicAdd(&ksum[((size_t)b * 4 + pq) * 512 + jl0 + jt0 + ji * 16 + quad * 4 + r], s);
      }
    }
  }
}

// ---------------- z[bh,p] = 1/(q2[bh,p,:].kmean[bh,:] + 1e-6) -----------------
// kmean reconstructed from ksum[b][pq=head][q*128+d] sums (flat-reshape algebra).
__global__ void z_k(const unsigned short* __restrict__ qbf, const float* __restrict__ ksum,
                    float* __restrict__ z) {
  const int wv = threadIdx.x >> 6, lane = threadIdx.x & 63;
  const int zbase = (blockIdx.x * 4 + wv) * 8;
  const int bh = zbase / NN;
  const int p0 = zbase % NN;
  const int b = bh >> 2, head = bh & 3;
  const float* ks = ksum + (size_t)bh * 512;
  const int d0 = lane * 2;
  const float km0 = (ks[d0] + ks[d0 + 128] + ks[d0 + 256] + ks[d0 + 384]) * (1.0f / 9216.0f);
  const float km1 = (ks[d0 + 1] + ks[d0 + 129] + ks[d0 + 257] + ks[d0 + 385]) * (1.0f / 9216.0f);
#pragma unroll
  for (int it = 0; it < 8; ++it) {
    const int p = p0 + it;
    const int pos = head * 2304 + (p >> 2);
    const int chb = (p & 3) * 128;
    const unsigned short* qp = qbf + ((size_t)b * NN + pos) * CC + chb + lane * 2;
    float dot = bf2f(qp[0]) * km0 + bf2f(qp[1]) * km1;
#pragma unroll
    for (int off = 1; off < 64; off <<= 1) dot += __shfl_xor(dot, off, 64);
    if (lane == 0) z[zbase + it] = 1.0f / (dot + 1e-6f);
  }
}

// ---------------- kv partials via MFMA ----------------------------------------
__launch_bounds__(256, 2)
__global__ void kv_mfma_k(const unsigned short* __restrict__ kbf, const float* __restrict__ x,
                          const float* __restrict__ rope, float* __restrict__ kvp) {
  __shared__ __align__(16) unsigned short sK[128 * 64];  // [d 128][q 64], swizzled octets
  const int s = blockIdx.x;   // 0..15 (q segment)
  const int bh = blockIdx.y;  // 0..31
  const int b = bh >> 2, head = bh & 3;
  const int tid = threadIdx.x;
  const int wv = tid >> 6, lane = tid & 63;
  const int row = lane & 15, quad = lane >> 4;
  const int e0 = (wv & 1) * 64, d0 = (wv >> 1) * 64;
  const int r = s >> 2;           // p = 4t + r
  const int t0 = (s & 3) * 576;   // t range [t0, t0+576), 9 chunks of 64

  const int qg = tid & 7;
  const int dg = (tid >> 3) * 4;  // first d row (0,4,..,124)
  const unsigned short* kbase = kbf + (size_t)b * NN * CC + head * HD + dg;
  const int pairb = head * 64 + (dg >> 1);

  f32x4 acc[4][4];
#pragma unroll
  for (int mi = 0; mi < 4; ++mi)
#pragma unroll
    for (int ni = 0; ni < 4; ++ni) acc[mi][ni] = (f32x4){0.f, 0.f, 0.f, 0.f};

  for (int ck = 0; ck < 9; ++ck) {
    const int tc = t0 + ck * 64;
    float4 a0[8], a1[8];
#pragma unroll
    for (int mi = 0; mi < 4; ++mi)
#pragma unroll
      for (int ks = 0; ks < 2; ++ks) {
        const float* xp = x + (size_t)(b * CC + r * 128 + e0 + mi * 16 + row) * NN +
                          head * 2304 + tc + ks * 32 + quad * 8;
        a0[mi * 2 + ks] = *(const float4*)xp;
        a1[mi * 2 + ks] = *(const float4*)(xp + 4);
      }
    {
      int p = 4 * (tc + qg * 8) + r;
      int col = p % 96;
      float rw0[8], rw1[8], rw2[8], rw3[8];
#pragma unroll
      for (int j = 0; j < 8; ++j) {
        uint2 kv2 = *(const uint2*)(kbase + (size_t)p * CC);
        const float* rp = rope + ((size_t)col * KMAX + pairb) * 2;
        float4 cs = *(const float4*)rp;  // c0 s0 c1 s1
        float re0 = bf2f((unsigned short)(kv2.x & 0xffffu));
        float im0 = bf2f((unsigned short)(kv2.x >> 16));
        float re1 = bf2f((unsigned short)(kv2.y & 0xffffu));
        float im1 = bf2f((unsigned short)(kv2.y >> 16));
        rw0[j] = cs.x * re0 - cs.y * im0;
        rw1[j] = cs.y * re0 + cs.x * im0;
        rw2[j] = cs.z * re1 - cs.w * im1;
        rw3[j] = cs.w * re1 + cs.z * im1;
        p += 4;
        col += 4;
        col = (col >= 96) ? col - 96 : col;
      }
#pragma unroll
      for (int rr = 0; rr < 4; ++rr) {
        const float* rw = (rr == 0) ? rw0 : (rr == 1) ? rw1 : (rr == 2) ? rw2 : rw3;
        const int d = dg + rr;
        uint4 pk;
        pk.x = pk2(rw[0], rw[1]);
        pk.y = pk2(rw[2], rw[3]);
        pk.z = pk2(rw[4], rw[5]);
        pk.w = pk2(rw[6], rw[7]);
        *(uint4*)&sK[(d * 8 + (qg ^ (d & 7))) * 8] = pk;
      }
    }
    __syncthreads();
#pragma unroll
    for (int ks = 0; ks < 2; ++ks) {
      bf16x8 bfr[4];
#pragma unroll
      for (int ni = 0; ni < 4; ++ni) {
        const int d = d0 + ni * 16 + row;
        const int o = (ks * 4 + quad) ^ (d & 7);
        bfr[ni] = *(const bf16x8*)&sK[(d * 8 + o) * 8];
      }
#pragma unroll
      for (int mi = 0; mi < 4; ++mi) {
        const int f = mi * 2 + ks;
        union { bf16x8 v; unsigned int u[4]; } af;
        af.u[0] = pk2(a0[f].x, a0[f].y);
        af.u[1] = pk2(a0[f].z, a0[f].w);
        af.u[2] = pk2(a1[f].x, a1[f].y);
        af.u[3] = pk2(a1[f].z, a1[f].w);
#pragma unroll
        for (int ni = 0; ni < 4; ++ni)
          acc[mi][ni] = __builtin_amdgcn_mfma_f32_16x16x32_bf16(af.v, bfr[ni], acc[mi][ni], 0, 0, 0);
      }
    }
    __syncthreads();
  }
  float* dst = kvp + (size_t)(s * 32 + bh) * (HD * HD);
#pragma unroll
  for (int mi = 0; mi < 4; ++mi) {
#pragma unroll
    for (int ni = 0; ni < 4; ++ni) {
#pragma unroll
      for (int rr = 0; rr < 4; ++rr) {
        const int e = e0 + mi * 16 + quad * 4 + rr;
        const int d = d0 + ni * 16 + row;
        dst[e * HD + d] = acc[mi][ni][rr];
      }
    }
  }
}

// ---------------- kv reduce: sum partials (already [e][d]), emit bf16 ---------
__global__ void kv_reduce_k(const float* __restrict__ kvp, unsigned short* __restrict__ kvtb) {
  int idx = blockIdx.x * 256 + threadIdx.x;  // 524288 = 32*128*128
  float ssum = 0.f;
#pragma unroll
  for (int i = 0; i < 16; ++i) ssum += kvp[(size_t)i * (32 * HD * HD) + idx];
  kvtb[idx] = f2bf(ssum * (1.0f / 9216.0f));
}

// ---------------- out (MFMA): out[b, head*128+e, pos] = z * sum_d qrope*kv ----
// q tile staged via gld16 with source-side octet swizzle (coalesced rows,
// conflict-free b128 LDS reads); stores routed through a 64x132 fp32 LDS tile
// (aliased over sQ) -> 512B-contiguous float4 stores.
__launch_bounds__(256)
__global__ void out_mfma_k(const unsigned short* __restrict__ qbf,
                           const unsigned short* __restrict__ kvtb,
                           const float* __restrict__ z, const float* __restrict__ rope,
                           float* __restrict__ out) {
  __shared__ __align__(16) float Ts[64 * 132];   // 33792 B; first 32KB doubles as sQ
  unsigned short* sQ = (unsigned short*)Ts;      // [pos 128][ch 128], chunk-swizzled
  const int bh = blockIdx.y, b = bh >> 2, head = bh & 3;
  const int pos0 = blockIdx.x * 128;
  const int tid = threadIdx.x, wv = tid >> 6, lane = tid & 63;
  const int row = lane & 15, quad = lane >> 4;
  const int e0 = (wv & 1) * 64;
  const int p0 = (wv >> 1) * 64;

  // stage q tile: 32KB, 8 gld16/thread, source pre-swizzled so LDS stays linear
#pragma unroll
  for (int it = 0; it < 8; ++it) {
    const int s = it * 256 + tid;
    const int srow = s >> 4, sc = s & 15;
    const int scs = (sc & 8) | ((sc & 7) ^ (srow & 7));
    gld16(qbf + ((size_t)b * NN + pos0 + srow) * CC + head * HD + scs * 8,
          &sQ[(size_t)(it * 256 + wv * 64) * 8]);
  }

  f32x4 acc[4][4];
#pragma unroll
  for (int mi = 0; mi < 4; ++mi)
#pragma unroll
    for (int ni = 0; ni < 4; ++ni) acc[mi][ni] = (f32x4){0.f, 0.f, 0.f, 0.f};

  int posn[4], coln[4];
#pragma unroll
  for (int ni = 0; ni < 4; ++ni) {
    posn[ni] = pos0 + p0 + ni * 16 + row;
    coln[ni] = posn[ni] % 96;
  }
  __syncthreads();  // barrier drains gld16

#pragma unroll
  for (int kt = 0; kt < HD; kt += 32) {
    bf16x8 af[4], bfr[4];
#pragma unroll
    for (int mi = 0; mi < 4; ++mi)
      af[mi] = *(const bf16x8*)&kvtb[((size_t)bh * HD + e0 + mi * 16 + row) * HD + kt + quad * 8];
#pragma unroll
    for (int ni = 0; ni < 4; ++ni) {
      const int posL = p0 + ni * 16 + row;
      const int chb = (kt >> 3) + quad;  // global 16B-chunk 0..15
      const int cl = (chb & 8) | ((chb & 7) ^ (posL & 7));
      const uint4 u = *(const uint4*)&sQ[posL * 128 + cl * 8];
      const int pairb = head * 64 + (kt >> 1) + quad * 4;
      const float* rp = rope + ((size_t)coln[ni] * KMAX + pairb) * 2;
      float4 r0 = *(const float4*)rp;        // c0 s0 c1 s1
      float4 r1 = *(const float4*)(rp + 4);  // c2 s2 c3 s3
      unsigned int uu[4] = {u.x, u.y, u.z, u.w};
      float cs[8] = {r0.x, r0.y, r0.z, r0.w, r1.x, r1.y, r1.z, r1.w};
      bf16x8 bb;
#pragma unroll
      for (int pr = 0; pr < 4; ++pr) {
        float re = bf2f((unsigned short)(uu[pr] & 0xffffu));
        float im = bf2f((unsigned short)(uu[pr] >> 16));
        float c = cs[2 * pr], s = cs[2 * pr + 1];
        bb[2 * pr] = (short)f2bf(c * re - s * im);
        bb[2 * pr + 1] = (short)f2bf(s * re + c * im);
      }
      bfr[ni] = bb;
    }
#pragma unroll
    for (int mi = 0; mi < 4; ++mi)
#pragma unroll
      for (int ni = 0; ni < 4; ++ni)
        acc[mi][ni] = __builtin_amdgcn_mfma_f32_16x16x32_bf16(af[mi], bfr[ni], acc[mi][ni], 0, 0, 0);
  }
  // z-scale in registers
#pragma unroll
  for (int ni = 0; ni < 4; ++ni) {
    const float zn = z[(size_t)bh * NN + posn[ni]];
#pragma unroll
    for (int mi = 0; mi < 4; ++mi)
#pragma unroll
      for (int r = 0; r < 4; ++r) acc[mi][ni][r] *= zn;
  }
  __syncthreads();  // all waves done reading sQ before Ts overwrite

  // two e-half passes through LDS -> coalesced float4 stores (512B rows)
#pragma unroll
  for (int h = 0; h < 2; ++h) {
    if ((wv & 1) == h) {
#pragma unroll
      for (int mi = 0; mi < 4; ++mi)
#pragma unroll
        for (int ni = 0; ni < 4; ++ni)
#pragma unroll
          for (int r = 0; r < 4; ++r) {
            const int eL = mi * 16 + quad * 4 + r;
            const int p = p0 + ni * 16 + row;
            Ts[eL * 132 + p] = acc[mi][ni][r];
          }
    }
    __syncthreads();
#pragma unroll
    for (int i = 0; i < 8; ++i) {
      const int eL = i * 8 + (tid >> 5);
      const int c = tid & 31;
      const float4 vv = *(const float4*)&Ts[eL * 132 + c * 4];
      *(float4*)&out[((size_t)b * CC + head * HD + h * 64 + eL) * NN + pos0 + c * 4] = vv;
    }
    __syncthreads();
  }
}

// ---------------- lepe: depthwise 3x3 conv of x, ADDS into d_out --------------
__global__ void lepe_k(const float* __restrict__ x, const float* __restrict__ lw,
                       const float* __restrict__ lb, float* __restrict__ out) {
  const int blk = blockIdx.x;  // B*C*9
  const int bc = blk / 9;
  const int tile = blk - bc * 9;
  const int ch = bc & (CC - 1);
  const float* wp = lw + ch * 9;
  float w[9];
#pragma unroll
  for (int t = 0; t < 9; ++t) w[t] = wp[t];
  const float bias = lb[ch];
  const float* xp = x + (size_t)bc * NN;
  const int pos = tile * 1024 + threadIdx.x * 4;
  const int pi = pos / 96;
  const int pj = pos - pi * 96;  // multiple of 4

  float4 o = *(const float4*)(out + (size_t)bc * NN + pos);  // RMW read early

  float a0 = bias, a1 = bias, a2 = bias, a3 = bias;
#pragma unroll
  for (int r = 0; r < 3; ++r) {
    const int y = pi + r - 1;
    if ((unsigned)y >= 96u) continue;
    const float* rowp = xp + y * 96 + pj;
    float4 M = *(const float4*)rowp;
    float Lv = (pj > 0) ? rowp[-1] : 0.f;
    float Rv = (pj < 92) ? rowp[4] : 0.f;
    const float w0 = w[r * 3 + 0], w1 = w[r * 3 + 1], w2 = w[r * 3 + 2];
    a0 += w0 * Lv + w1 * M.x + w2 * M.y;
    a1 += w0 * M.x + w1 * M.y + w2 * M.z;
    a2 += w0 * M.y + w1 * M.z + w2 * M.w;
    a3 += w0 * M.z + w1 * M.w + w2 * Rv;
  }
  o.x += a0; o.y += a1; o.z += a2; o.w += a3;
  *(float4*)(out + (size_t)bc * NN + pos) = o;
}

extern "C" void kernel_launch(void* const* d_in, const int* in_sizes, int n_in,
                              void* d_out, int out_size, void* d_ws, size_t ws_size,
                              hipStream_t stream) {
  const float* x = (const float*)d_in[0];
  const float* Wqk = (const float*)d_in[1];
  const float* bqk = (const float*)d_in[2];
  const float* lw = (const float*)d_in[3];
  const float* lb = (const float*)d_in[4];
  float* out = (float*)d_out;
  char* ws = (char*)d_ws;
  // ws layout: ksum overlays the kvp region head (dead by the time kv_mfma
  // writes kvp, since z_k runs first). xtb for ALL batches lives in d_out.
  unsigned short* qbf = (unsigned short*)(ws);                 // 75,497,472 B
  unsigned short* kbf = (unsigned short*)(ws + 75497472);      // 75,497,472 B
  float* rope = (float*)(ws + 150994944);                      //    196,608 B
  float* z = (float*)(ws + 151207936);                         //  1,179,648 B
  float* kvp = (float*)(ws + 152387584);                       // 33,554,432 B
  float* ksum = (float*)(ws + 152387584);                      //     65,536 B (overlay)
  unsigned short* kvtb = (unsigned short*)(ws + 185942016);    //  1,048,576 B
  unsigned short* Wbf = (unsigned short*)(ws + 188039168);     //  1,048,576 B
  unsigned short* xtb = (unsigned short*)d_out;                // 75,497,472 B (scratch in out)

  hipMemsetAsync(ksum, 0, (size_t)BB * 4 * 512 * sizeof(float), stream);
  conv_w_k<<<dim3(512), dim3(256), 0, stream>>>(Wqk, Wbf);
  rope_table_k<<<dim3(96), dim3(256), 0, stream>>>(rope);
  transpose_all_k<<<dim3(144, 8, 8), dim3(256), 0, stream>>>(x, xtb);
  gemm_qk_mfma<<<dim3(4608), dim3(256), 0, stream>>>(xtb, Wbf, bqk, qbf, kbf, ksum);
  z_k<<<dim3(9216), dim3(256), 0, stream>>>(qbf, ksum, z);
  kv_mfma_k<<<dim3(16, 32), dim3(256), 0, stream>>>(kbf, x, rope, kvp);
  kv_reduce_k<<<dim3(2048), dim3(256), 0, stream>>>(kvp, kvtb);
  out_mfma_k<<<dim3(72, 32), dim3(256), 0, stream>>>(qbf, kvtb, z, rope, out);
  lepe_k<<<dim3(36864), dim3(256), 0, stream>>>(x, lw, lb, out);
}

// Round 6
// 698.167 us; speedup vs baseline: 1.3269x; 1.0216x over previous
//
#include <hip/hip_runtime.h>
#include <hip/hip_bf16.h>
#include <cstdint>

// Problem constants
#define BB 8
#define CC 512
#define HH 96
#define NN 9216      // 96*96
#define HEADS 4
#define HD 128
#define KMAX 256     // c/2

typedef unsigned short ushort_t;
typedef __attribute__((ext_vector_type(8))) short bf16x8;
typedef __attribute__((ext_vector_type(4))) float f32x4;

__device__ __forceinline__ unsigned short f2bf(float f) {
  unsigned int u = __float_as_uint(f);
  u += 0x7fffu + ((u >> 16) & 1u);   // RNE; values are finite here
  return (unsigned short)(u >> 16);
}
__device__ __forceinline__ float bf2f(unsigned short s) {
  return __uint_as_float(((unsigned int)s) << 16);
}
__device__ __forceinline__ unsigned int pk2(float lo, float hi) {
  return (unsigned int)f2bf(lo) | ((unsigned int)f2bf(hi) << 16);
}

// async global->LDS 16B: lds dest must be wave-uniform base; HW scatters lane i at +16*i
__device__ __forceinline__ void gld16(const void* g, void* l) {
  __builtin_amdgcn_global_load_lds(
      (const __attribute__((address_space(1))) unsigned int*)(uintptr_t)g,
      (__attribute__((address_space(3))) unsigned int*)(unsigned int)(uintptr_t)l,
      16, 0, 0);
}

// ---------------- rope table: cos/sin[col][kk], col = pos % 96 ----------------
__global__ void rope_table_k(float* __restrict__ rope) {
  int t = blockIdx.x * 256 + threadIdx.x;
  if (t >= HH * KMAX) return;
  int col = t >> 8;
  int kk = t & (KMAX - 1);
  float theta = powf(10000.0f, -((float)kk) / (float)KMAX);
  float ang = (float)col * theta;
  float s, c;
  sincosf(ang, &s, &c);
  rope[2 * t] = c;
  rope[2 * t + 1] = s;
}

// ---------------- W fp32 -> bf16 ----------------------------------------------
__global__ void conv_w_k(const float* __restrict__ W, unsigned short* __restrict__ Wbf) {
  int t = blockIdx.x * 256 + threadIdx.x;  // 131072 float4s
  float4 v = *(const float4*)(W + (size_t)t * 4);
  unsigned int lo = (unsigned int)f2bf(v.x) | ((unsigned int)f2bf(v.y) << 16);
  unsigned int hi = (unsigned int)f2bf(v.z) | ((unsigned int)f2bf(v.w) << 16);
  *(uint2*)(Wbf + (size_t)t * 4) = make_uint2(lo, hi);
}

// ------- all-batch transpose: x[b][ch][pos] fp32 -> xt[b][pos][ch] bf16 -------
__global__ void transpose_all_k(const float* __restrict__ x, unsigned short* __restrict__ xt) {
  __shared__ unsigned short T[64 * 72];  // [pos][ch], pad 8 (row 144B, 16B-aligned)
  const int pos0 = blockIdx.x * 64;
  const int ch0 = blockIdx.y * 64;
  const int b = blockIdx.z;
  const int tid = threadIdx.x;
#pragma unroll
  for (int i = 0; i < 4; ++i) {
    int fi = i * 256 + tid;          // 0..1023
    int ch = fi >> 4, p4 = fi & 15;  // 64 ch x 16 float4
    float4 v = *(const float4*)(x + ((size_t)b * CC + ch0 + ch) * NN + pos0 + p4 * 4);
    T[(p4 * 4 + 0) * 72 + ch] = f2bf(v.x);
    T[(p4 * 4 + 1) * 72 + ch] = f2bf(v.y);
    T[(p4 * 4 + 2) * 72 + ch] = f2bf(v.z);
    T[(p4 * 4 + 3) * 72 + ch] = f2bf(v.w);
  }
  __syncthreads();
#pragma unroll
  for (int i = 0; i < 2; ++i) {
    int s = i * 256 + tid;          // 0..511
    int p = s >> 3, cc = s & 7;     // 64 rows x 8 chunks of 16B
    uint4 u = *(const uint4*)&T[p * 72 + cc * 8];
    *(uint4*)(xt + ((size_t)b * NN + pos0 + p) * CC + ch0 + cc * 8) = u;
  }
}

// ---------------- qk GEMM (MFMA bf16), 2-phase prefetch -----------------------
// Swapped-operand MFMA (D reg-dim = 4 consecutive j -> uint2 stores).
// T3-minimal schedule: double-buffered LDS, STAGE(t+1) issued BEFORE compute(t),
// counted s_waitcnt vmcnt(8) + raw s_barrier (never drain to 0 mid-loop).
// k-half waves write per-(block,wave-half) column-sum partials (NO atomics).
__launch_bounds__(256)
__global__ void gemm_qk_mfma(const unsigned short* __restrict__ xtall,
                             const unsigned short* __restrict__ Wbf,
                             const float* __restrict__ bqk,
                             unsigned short* __restrict__ qout,
                             unsigned short* __restrict__ kout,
                             float* __restrict__ kpart) {
  __shared__ __align__(16) unsigned short sA[2 * 128 * 64];
  __shared__ __align__(16) unsigned short sB[2 * 128 * 64];
  const int flat = blockIdx.x;                    // 0..4607
  const int bn = (flat >> 3) & 7;                 // j block 0..7
  const int g = ((flat >> 6) << 3) | (flat & 7);  // A-tile id 0..575
  const int b = g / 72;
  const int mblk = g - b * 72;                    // 0..71
  const int m0 = mblk * 128;                      // pos within batch
  const int tid = threadIdx.x;
  const int wv = tid >> 6, lane = tid & 63;
  const int j0 = bn * 128;
  const unsigned short* xt = xtall + (size_t)b * NN * CC;
  const int row = lane & 15, quad = lane >> 4;
  const int jt0 = (wv & 1) * 64, pt0 = (wv >> 1) * 64;
  f32x4 acc[4][4];  // [ji][pi]
#pragma unroll
  for (int ji = 0; ji < 4; ++ji)
#pragma unroll
    for (int pi = 0; pi < 4; ++pi) acc[ji][pi] = (f32x4){0.f, 0.f, 0.f, 0.f};

  auto STAGE = [&](int kt, int buf) {
#pragma unroll
    for (int it = 0; it < 4; ++it) {
      int s = it * 256 + tid;                 // LDS slot (16B units)
      int srow = s >> 3;                      // tile row 0..127
      int sc = (s & 7) ^ (srow & 7);          // swizzled chunk -> global chunk
      int ldsoff = buf * 8192 + (it * 256 + wv * 64) * 8;  // wave-uniform base
      gld16(xt + (size_t)(m0 + srow) * CC + kt + sc * 8, &sA[ldsoff]);
      gld16(Wbf + (size_t)(j0 + srow) * CC + kt + sc * 8, &sB[ldsoff]);
    }
  };

  STAGE(0, 0);
  for (int ktI = 0; ktI < 8; ++ktI) {
    const int cur = ktI & 1;
    if (ktI < 7) {
      STAGE((ktI + 1) * 64, cur ^ 1);
      asm volatile("s_waitcnt vmcnt(8)" ::: "memory");  // wait only the 8 older loads
    } else {
      asm volatile("s_waitcnt vmcnt(0)" ::: "memory");
    }
    __builtin_amdgcn_sched_barrier(0);
    __builtin_amdgcn_s_barrier();
#pragma unroll
    for (int ks = 0; ks < 2; ++ks) {
      bf16x8 aw[4], ax[4];
      const int chunk = (ks * 4 + quad) ^ (row & 7);
#pragma unroll
      for (int ji = 0; ji < 4; ++ji)
        aw[ji] = *(const bf16x8*)&sB[cur * 8192 + ((jt0 + ji * 16 + row) * 8 + chunk) * 8];
#pragma unroll
      for (int pi = 0; pi < 4; ++pi)
        ax[pi] = *(const bf16x8*)&sA[cur * 8192 + ((pt0 + pi * 16 + row) * 8 + chunk) * 8];
#pragma unroll
      for (int ji = 0; ji < 4; ++ji)
#pragma unroll
        for (int pi = 0; pi < 4; ++pi)
          acc[ji][pi] = __builtin_amdgcn_mfma_f32_16x16x32_bf16(aw[ji], ax[pi], acc[ji][pi], 0, 0, 0);
    }
    __builtin_amdgcn_s_barrier();  // reads of buf[cur] done before next STAGE overwrites it
  }
  // epilogue: D layout: j = jt0 + ji*16 + quad*4 + r, pos = pt0 + pi*16 + row.
  unsigned short* dst = (j0 < CC) ? qout : kout;
  const int jl0 = j0 & (CC - 1);
#pragma unroll
  for (int ji = 0; ji < 4; ++ji) {
    const float4 bb = *(const float4*)&bqk[j0 + jt0 + ji * 16 + quad * 4];
    const float bj[4] = {bb.x, bb.y, bb.z, bb.w};
    float sacc[4] = {0.f, 0.f, 0.f, 0.f};
#pragma unroll
    for (int pi = 0; pi < 4; ++pi) {
      float v[4];
#pragma unroll
      for (int r = 0; r < 4; ++r) {
        float t = acc[ji][pi][r] + bj[r];
        v[r] = t > 0.f ? t + 1.f : __expf(t);   // elu(t)+1 == exp(t) for t<=0
        sacc[r] += v[r];
      }
      const int posm = m0 + pt0 + pi * 16 + row;
      uint2 pkd = make_uint2(pk2(v[0], v[1]), pk2(v[2], v[3]));
      *(uint2*)&dst[((size_t)b * NN + posm) * CC + jl0 + jt0 + ji * 16 + quad * 4] = pkd;
    }
    if (j0 >= CC) {  // k-half: fold column sums over this wave's 64 pos
#pragma unroll
      for (int r = 0; r < 4; ++r) {
        float s = sacc[r];
        s += __shfl_xor(s, 1);
        s += __shfl_xor(s, 2);
        s += __shfl_xor(s, 4);
        s += __shfl_xor(s, 8);
        if (row == 0)  // per-(block, wave-half) private slot: NO atomics
          kpart[((size_t)(b * 72 + mblk) * 2 + (pt0 >> 6)) * 512 +
                jl0 + jt0 + ji * 16 + quad * 4 + r] = s;
      }
    }
  }
}

// ---------------- kmean from partials -----------------------------------------
__global__ void kmean_k(const float* __restrict__ kpart, float* __restrict__ kmean) {
  int idx = blockIdx.x * 256 + threadIdx.x;  // 4096
  int bh = idx >> 7, d = idx & 127;
  int b = bh >> 2, head = bh & 3;
  float s = 0.f;
  for (int i = 0; i < 36; ++i) {
    const float* p = kpart + ((size_t)(b * 72 + head * 18) * 2 + i) * 512 + d;
    s += p[0] + p[128] + p[256] + p[384];
  }
  kmean[idx] = s * (1.0f / 9216.0f);
}

// ---------------- z[bh,p] = 1/(q2[bh,p,:].kmean[bh,:] + 1e-6) -----------------
__global__ void z_k(const unsigned short* __restrict__ qbf, const float* __restrict__ kmean,
                    float* __restrict__ z) {
  const int wv = threadIdx.x >> 6, lane = threadIdx.x & 63;
  const int zbase = (blockIdx.x * 4 + wv) * 8;
  const int bh = zbase / NN;
  const int p0 = zbase % NN;
  const int b = bh >> 2, head = bh & 3;
  const float km0 = kmean[bh * 128 + lane * 2];
  const float km1 = kmean[bh * 128 + lane * 2 + 1];
#pragma unroll
  for (int it = 0; it < 8; ++it) {
    const int p = p0 + it;
    const int pos = head * 2304 + (p >> 2);
    const int chb = (p & 3) * 128;
    const unsigned short* qp = qbf + ((size_t)b * NN + pos) * CC + chb + lane * 2;
    float dot = bf2f(qp[0]) * km0 + bf2f(qp[1]) * km1;
#pragma unroll
    for (int off = 1; off < 64; off <<= 1) dot += __shfl_xor(dot, off, 64);
    if (lane == 0) z[zbase + it] = 1.0f / (dot + 1e-6f);
  }
}

// ---------------- kv partials via MFMA ----------------------------------------
__launch_bounds__(256, 2)
__global__ void kv_mfma_k(const unsigned short* __restrict__ kbf, const float* __restrict__ x,
                          const float* __restrict__ rope, float* __restrict__ kvp) {
  __shared__ __align__(16) unsigned short sK[128 * 64];  // [d 128][q 64], swizzled octets
  const int s = blockIdx.x;   // 0..15 (q segment)
  const int bh = blockIdx.y;  // 0..31
  const int b = bh >> 2, head = bh & 3;
  const int tid = threadIdx.x;
  const int wv = tid >> 6, lane = tid & 63;
  const int row = lane & 15, quad = lane >> 4;
  const int e0 = (wv & 1) * 64, d0 = (wv >> 1) * 64;
  const int r = s >> 2;           // p = 4t + r
  const int t0 = (s & 3) * 576;   // t range [t0, t0+576), 9 chunks of 64

  const int qg = tid & 7;
  const int dg = (tid >> 3) * 4;  // first d row (0,4,..,124)
  const unsigned short* kbase = kbf + (size_t)b * NN * CC + head * HD + dg;
  const int pairb = head * 64 + (dg >> 1);

  f32x4 acc[4][4];
#pragma unroll
  for (int mi = 0; mi < 4; ++mi)
#pragma unroll
    for (int ni = 0; ni < 4; ++ni) acc[mi][ni] = (f32x4){0.f, 0.f, 0.f, 0.f};

  for (int ck = 0; ck < 9; ++ck) {
    const int tc = t0 + ck * 64;
    float4 a0[8], a1[8];
#pragma unroll
    for (int mi = 0; mi < 4; ++mi)
#pragma unroll
      for (int ks = 0; ks < 2; ++ks) {
        const float* xp = x + (size_t)(b * CC + r * 128 + e0 + mi * 16 + row) * NN +
                          head * 2304 + tc + ks * 32 + quad * 8;
        a0[mi * 2 + ks] = *(const float4*)xp;
        a1[mi * 2 + ks] = *(const float4*)(xp + 4);
      }
    {
      int p = 4 * (tc + qg * 8) + r;
      int col = p % 96;
      float rw0[8], rw1[8], rw2[8], rw3[8];
#pragma unroll
      for (int j = 0; j < 8; ++j) {
        uint2 kv2 = *(const uint2*)(kbase + (size_t)p * CC);
        const float* rp = rope + ((size_t)col * KMAX + pairb) * 2;
        float4 cs = *(const float4*)rp;  // c0 s0 c1 s1
        float re0 = bf2f((unsigned short)(kv2.x & 0xffffu));
        float im0 = bf2f((unsigned short)(kv2.x >> 16));
        float re1 = bf2f((unsigned short)(kv2.y & 0xffffu));
        float im1 = bf2f((unsigned short)(kv2.y >> 16));
        rw0[j] = cs.x * re0 - cs.y * im0;
        rw1[j] = cs.y * re0 + cs.x * im0;
        rw2[j] = cs.z * re1 - cs.w * im1;
        rw3[j] = cs.w * re1 + cs.z * im1;
        p += 4;
        col += 4;
        col = (col >= 96) ? col - 96 : col;
      }
#pragma unroll
      for (int rr = 0; rr < 4; ++rr) {
        const float* rw = (rr == 0) ? rw0 : (rr == 1) ? rw1 : (rr == 2) ? rw2 : rw3;
        const int d = dg + rr;
        uint4 pk;
        pk.x = pk2(rw[0], rw[1]);
        pk.y = pk2(rw[2], rw[3]);
        pk.z = pk2(rw[4], rw[5]);
        pk.w = pk2(rw[6], rw[7]);
        *(uint4*)&sK[(d * 8 + (qg ^ (d & 7))) * 8] = pk;
      }
    }
    __syncthreads();
#pragma unroll
    for (int ks = 0; ks < 2; ++ks) {
      bf16x8 bfr[4];
#pragma unroll
      for (int ni = 0; ni < 4; ++ni) {
        const int d = d0 + ni * 16 + row;
        const int o = (ks * 4 + quad) ^ (d & 7);
        bfr[ni] = *(const bf16x8*)&sK[(d * 8 + o) * 8];
      }
#pragma unroll
      for (int mi = 0; mi < 4; ++mi) {
        const int f = mi * 2 + ks;
        union { bf16x8 v; unsigned int u[4]; } af;
        af.u[0] = pk2(a0[f].x, a0[f].y);
        af.u[1] = pk2(a0[f].z, a0[f].w);
        af.u[2] = pk2(a1[f].x, a1[f].y);
        af.u[3] = pk2(a1[f].z, a1[f].w);
#pragma unroll
        for (int ni = 0; ni < 4; ++ni)
          acc[mi][ni] = __builtin_amdgcn_mfma_f32_16x16x32_bf16(af.v, bfr[ni], acc[mi][ni], 0, 0, 0);
      }
    }
    __syncthreads();
  }
  float* dst = kvp + (size_t)(s * 32 + bh) * (HD * HD);
#pragma unroll
  for (int mi = 0; mi < 4; ++mi) {
#pragma unroll
    for (int ni = 0; ni < 4; ++ni) {
#pragma unroll
      for (int rr = 0; rr < 4; ++rr) {
        const int e = e0 + mi * 16 + quad * 4 + rr;
        const int d = d0 + ni * 16 + row;
        dst[e * HD + d] = acc[mi][ni][rr];
      }
    }
  }
}

// ---------------- kv reduce: sum partials (already [e][d]), emit bf16 ---------
__global__ void kv_reduce_k(const float* __restrict__ kvp, unsigned short* __restrict__ kvtb) {
  int idx = blockIdx.x * 256 + threadIdx.x;  // 524288 = 32*128*128
  float ssum = 0.f;
#pragma unroll
  for (int i = 0; i < 16; ++i) ssum += kvp[(size_t)i * (32 * HD * HD) + idx];
  kvtb[idx] = f2bf(ssum * (1.0f / 9216.0f));
}

// ---------------- out (MFMA): out[b, head*128+e, pos] = z * sum_d qrope*kv ----
__launch_bounds__(256)
__global__ void out_mfma_k(const unsigned short* __restrict__ qbf,
                           const unsigned short* __restrict__ kvtb,
                           const float* __restrict__ z, const float* __restrict__ rope,
                           float* __restrict__ out) {
  __shared__ __align__(16) float Ts[64 * 132];   // 33792 B; first 32KB doubles as sQ
  unsigned short* sQ = (unsigned short*)Ts;      // [pos 128][ch 128], chunk-swizzled
  const int bh = blockIdx.y, b = bh >> 2, head = bh & 3;
  const int pos0 = blockIdx.x * 128;
  const int tid = threadIdx.x, wv = tid >> 6, lane = tid & 63;
  const int row = lane & 15, quad = lane >> 4;
  const int e0 = (wv & 1) * 64;
  const int p0 = (wv >> 1) * 64;

  // stage q tile: 32KB, 8 gld16/thread, source pre-swizzled so LDS stays linear
#pragma unroll
  for (int it = 0; it < 8; ++it) {
    const int s = it * 256 + tid;
    const int srow = s >> 4, sc = s & 15;
    const int scs = (sc & 8) | ((sc & 7) ^ (srow & 7));
    gld16(qbf + ((size_t)b * NN + pos0 + srow) * CC + head * HD + scs * 8,
          &sQ[(size_t)(it * 256 + wv * 64) * 8]);
  }

  f32x4 acc[4][4];
#pragma unroll
  for (int mi = 0; mi < 4; ++mi)
#pragma unroll
    for (int ni = 0; ni < 4; ++ni) acc[mi][ni] = (f32x4){0.f, 0.f, 0.f, 0.f};

  int posn[4], coln[4];
#pragma unroll
  for (int ni = 0; ni < 4; ++ni) {
    posn[ni] = pos0 + p0 + ni * 16 + row;
    coln[ni] = posn[ni] % 96;
  }
  __syncthreads();  // barrier drains gld16

#pragma unroll
  for (int kt = 0; kt < HD; kt += 32) {
    bf16x8 af[4], bfr[4];
#pragma unroll
    for (int mi = 0; mi < 4; ++mi)
      af[mi] = *(const bf16x8*)&kvtb[((size_t)bh * HD + e0 + mi * 16 + row) * HD + kt + quad * 8];
#pragma unroll
    for (int ni = 0; ni < 4; ++ni) {
      const int posL = p0 + ni * 16 + row;
      const int chb = (kt >> 3) + quad;  // global 16B-chunk 0..15
      const int cl = (chb & 8) | ((chb & 7) ^ (posL & 7));
      const uint4 u = *(const uint4*)&sQ[posL * 128 + cl * 8];
      const int pairb = head * 64 + (kt >> 1) + quad * 4;
      const float* rp = rope + ((size_t)coln[ni] * KMAX + pairb) * 2;
      float4 r0 = *(const float4*)rp;        // c0 s0 c1 s1
      float4 r1 = *(const float4*)(rp + 4);  // c2 s2 c3 s3
      unsigned int uu[4] = {u.x, u.y, u.z, u.w};
      float cs[8] = {r0.x, r0.y, r0.z, r0.w, r1.x, r1.y, r1.z, r1.w};
      bf16x8 bb;
#pragma unroll
      for (int pr = 0; pr < 4; ++pr) {
        float re = bf2f((unsigned short)(uu[pr] & 0xffffu));
        float im = bf2f((unsigned short)(uu[pr] >> 16));
        float c = cs[2 * pr], s = cs[2 * pr + 1];
        bb[2 * pr] = (short)f2bf(c * re - s * im);
        bb[2 * pr + 1] = (short)f2bf(s * re + c * im);
      }
      bfr[ni] = bb;
    }
#pragma unroll
    for (int mi = 0; mi < 4; ++mi)
#pragma unroll
      for (int ni = 0; ni < 4; ++ni)
        acc[mi][ni] = __builtin_amdgcn_mfma_f32_16x16x32_bf16(af[mi], bfr[ni], acc[mi][ni], 0, 0, 0);
  }
  // z-scale in registers
#pragma unroll
  for (int ni = 0; ni < 4; ++ni) {
    const float zn = z[(size_t)bh * NN + posn[ni]];
#pragma unroll
    for (int mi = 0; mi < 4; ++mi)
#pragma unroll
      for (int r = 0; r < 4; ++r) acc[mi][ni][r] *= zn;
  }
  __syncthreads();  // all waves done reading sQ before Ts overwrite

  // two e-half passes through LDS -> coalesced float4 stores (512B rows)
#pragma unroll
  for (int h = 0; h < 2; ++h) {
    if ((wv & 1) == h) {
#pragma unroll
      for (int mi = 0; mi < 4; ++mi)
#pragma unroll
        for (int ni = 0; ni < 4; ++ni)
#pragma unroll
          for (int r = 0; r < 4; ++r) {
            const int eL = mi * 16 + quad * 4 + r;
            const int p = p0 + ni * 16 + row;
            Ts[eL * 132 + p] = acc[mi][ni][r];
          }
    }
    __syncthreads();
#pragma unroll
    for (int i = 0; i < 8; ++i) {
      const int eL = i * 8 + (tid >> 5);
      const int c = tid & 31;
      const float4 vv = *(const float4*)&Ts[eL * 132 + c * 4];
      *(float4*)&out[((size_t)b * CC + head * HD + h * 64 + eL) * NN + pos0 + c * 4] = vv;
    }
    __syncthreads();
  }
}

// ---------------- lepe: depthwise 3x3 conv of x, ADDS into d_out --------------
__global__ void lepe_k(const float* __restrict__ x, const float* __restrict__ lw,
                       const float* __restrict__ lb, float* __restrict__ out) {
  const int blk = blockIdx.x;  // B*C*9
  const int bc = blk / 9;
  const int tile = blk - bc * 9;
  const int ch = bc & (CC - 1);
  const float* wp = lw + ch * 9;
  float w[9];
#pragma unroll
  for (int t = 0; t < 9; ++t) w[t] = wp[t];
  const float bias = lb[ch];
  const float* xp = x + (size_t)bc * NN;
  const int pos = tile * 1024 + threadIdx.x * 4;
  const int pi = pos / 96;
  const int pj = pos - pi * 96;  // multiple of 4

  float4 o = *(const float4*)(out + (size_t)bc * NN + pos);  // RMW read early

  float a0 = bias, a1 = bias, a2 = bias, a3 = bias;
#pragma unroll
  for (int r = 0; r < 3; ++r) {
    const int y = pi + r - 1;
    if ((unsigned)y >= 96u) continue;
    const float* rowp = xp + y * 96 + pj;
    float4 M = *(const float4*)rowp;
    float Lv = (pj > 0) ? rowp[-1] : 0.f;
    float Rv = (pj < 92) ? rowp[4] : 0.f;
    const float w0 = w[r * 3 + 0], w1 = w[r * 3 + 1], w2 = w[r * 3 + 2];
    a0 += w0 * Lv + w1 * M.x + w2 * M.y;
    a1 += w0 * M.x + w1 * M.y + w2 * M.z;
    a2 += w0 * M.y + w1 * M.z + w2 * M.w;
    a3 += w0 * M.z + w1 * M.w + w2 * Rv;
  }
  o.x += a0; o.y += a1; o.z += a2; o.w += a3;
  *(float4*)(out + (size_t)bc * NN + pos) = o;
}

extern "C" void kernel_launch(void* const* d_in, const int* in_sizes, int n_in,
                              void* d_out, int out_size, void* d_ws, size_t ws_size,
                              hipStream_t stream) {
  const float* x = (const float*)d_in[0];
  const float* Wqk = (const float*)d_in[1];
  const float* bqk = (const float*)d_in[2];
  const float* lw = (const float*)d_in[3];
  const float* lb = (const float*)d_in[4];
  float* out = (float*)d_out;
  char* ws = (char*)d_ws;
  // ws layout: kpart+kmean overlay the kvp region head (dead until kv_mfma,
  // which runs after z_k). xtb for ALL batches lives in d_out.
  unsigned short* qbf = (unsigned short*)(ws);                 // 75,497,472 B
  unsigned short* kbf = (unsigned short*)(ws + 75497472);      // 75,497,472 B
  float* rope = (float*)(ws + 150994944);                      //    196,608 B
  float* z = (float*)(ws + 151207936);                         //  1,179,648 B
  float* kvp = (float*)(ws + 152387584);                       // 33,554,432 B
  float* kpart = (float*)(ws + 152387584);                     //  1,179,648 B (overlay)
  float* kmean = (float*)(ws + 152387584 + 1179648);           //     16,384 B (overlay)
  unsigned short* kvtb = (unsigned short*)(ws + 185942016);    //  1,048,576 B
  unsigned short* Wbf = (unsigned short*)(ws + 188039168);     //  1,048,576 B
  unsigned short* xtb = (unsigned short*)d_out;                // 75,497,472 B (scratch in out)

  conv_w_k<<<dim3(512), dim3(256), 0, stream>>>(Wqk, Wbf);
  rope_table_k<<<dim3(96), dim3(256), 0, stream>>>(rope);
  transpose_all_k<<<dim3(144, 8, 8), dim3(256), 0, stream>>>(x, xtb);
  gemm_qk_mfma<<<dim3(4608), dim3(256), 0, stream>>>(xtb, Wbf, bqk, qbf, kbf, kpart);
  kmean_k<<<dim3(16), dim3(256), 0, stream>>>(kpart, kmean);
  z_k<<<dim3(9216), dim3(256), 0, stream>>>(qbf, kmean, z);
  kv_mfma_k<<<dim3(16, 32), dim3(256), 0, stream>>>(kbf, x, rope, kvp);
  kv_reduce_k<<<dim3(2048), dim3(256), 0, stream>>>(kvp, kvtb);
  out_mfma_k<<<dim3(72, 32), dim3(256), 0, stream>>>(qbf, kvtb, z, rope, out);
  lepe_k<<<dim3(36864), dim3(256), 0, stream>>>(x, lw, lb, out);
}